// Round 6
// baseline (562.194 us; speedup 1.0000x reference)
//
#include <hip/hip_runtime.h>
#include <hip/hip_bf16.h>
#include <cstdint>
#include <cstddef>

typedef __hip_bfloat16 bf16;
typedef __attribute__((ext_vector_type(8))) short short8;
typedef __attribute__((ext_vector_type(4))) short short4v;
typedef __attribute__((ext_vector_type(4))) float floatx4;
typedef unsigned long long u64;

#define DEVI static __device__ __forceinline__

DEVI void load_lds16(const void* g, void* l) {
  __builtin_amdgcn_global_load_lds((const __attribute__((address_space(1))) unsigned int*)g,
                                   (__attribute__((address_space(3))) unsigned int*)l, 16, 0, 0);
}
DEVI short8 ld8(const bf16* p) { return *(const short8*)p; }
DEVI floatx4 mfma16(short8 a, short8 b, floatx4 c) {
  return __builtin_amdgcn_mfma_f32_16x16x32_bf16(a, b, c, 0, 0, 0);
}
DEVI short bfb(float f) { bf16 h = __float2bfloat16(f); return __builtin_bit_cast(short, h); }
DEVI float fbf(short s) { bf16 h = __builtin_bit_cast(bf16, s); return __bfloat162float(h); }

// ---------------- fused prep: x->bf16 + adj bits + all 6 weight transposes ----------------
// Block budget: 4096 (x/adj) + 4096 (Wq,Wk,Wv,Wo) + 2048 (W1) + 2048 (W2) = 12288.
DEVI void tr_tile(const float* in, bf16* out, int R, int C, int bx, int by) {
  __shared__ float t[32][33];
  int c0 = bx * 32, r0 = by * 32;
  int tx = threadIdx.x & 31, ty = threadIdx.x >> 5;
#pragma unroll
  for (int i = 0; i < 32; i += 8) t[ty + i][tx] = in[(size_t)(r0 + ty + i) * C + c0 + tx];
  __syncthreads();
#pragma unroll
  for (int i = 0; i < 32; i += 8)
    out[(size_t)(c0 + ty + i) * R + r0 + tx] = __float2bfloat16(t[tx][ty + i]);
}

__global__ __launch_bounds__(256)
void prep_all(const float* __restrict__ x, bf16* __restrict__ xb,
              const float* __restrict__ adj, u64* __restrict__ bits,
              const float* Wq, const float* Wk, const float* Wv, const float* Wo,
              const float* W1, const float* W2,
              bf16* Wqkvt, bf16* Wot, bf16* W1t, bf16* W2t) {
  int id = blockIdx.x;
  if (id < 4096) {
    const int row = id, tid = threadIdx.x;
    const int wave = tid >> 6, lane = tid & 63;
    float4 v = ((const float4*)(x + (size_t)row * 1024))[tid];
    bf16* o = xb + (size_t)row * 1024 + tid * 4;
    o[0] = __float2bfloat16(v.x); o[1] = __float2bfloat16(v.y);
    o[2] = __float2bfloat16(v.z); o[3] = __float2bfloat16(v.w);
    const float* arow = adj + (size_t)row * 4096;
#pragma unroll
    for (int it = 0; it < 16; it++) {
      int col = it * 256 + tid;
      u64 m = __ballot(arow[col] != 0.f);
      if (lane == 0) bits[(size_t)row * 64 + it * 4 + wave] = m;
    }
  } else if (id < 8192) {
    int q = id - 4096, w = q >> 10, t = q & 1023;
    const float* in = w == 0 ? Wq : w == 1 ? Wk : w == 2 ? Wv : Wo;
    bf16* out = w == 0 ? Wqkvt : w == 1 ? Wqkvt + 1024ull * 1024
              : w == 2 ? Wqkvt + 2048ull * 1024 : Wot;
    tr_tile(in, out, 1024, 1024, t & 31, t >> 5);
  } else if (id < 10240) {
    int t = id - 8192;
    tr_tile(W1, W1t, 1024, 2048, t & 63, t >> 6);
  } else {
    int t = id - 10240;
    tr_tile(W2, W2t, 2048, 1024, t & 31, t >> 5);
  }
}

// ---------------- plain V^T build: out[dh][n] = V[n][dh] ----------------
__global__ __launch_bounds__(256)
void tr_bf16t(const bf16* __restrict__ in, bf16* __restrict__ out, int inLd) {
  __shared__ bf16 t[32][33];
  int c0 = blockIdx.x * 32, r0 = blockIdx.y * 32;
  int tx = threadIdx.x, ty = threadIdx.y;
#pragma unroll
  for (int i = 0; i < 32; i += 8) t[ty + i][tx] = in[(size_t)(r0 + ty + i) * inLd + c0 + tx];
  __syncthreads();
#pragma unroll
  for (int i = 0; i < 32; i += 8)
    out[(size_t)(c0 + ty + i) * 4096 + r0 + tx] = t[tx][ty + i];
}

// ---------------- bf16 GEMM, C = A[M][K] @ Bt[N][K]^T, tile 128 x BN ----------------
// Pipelined K-loop: 3 LDS buffers, loads 2 tiles in flight, raw s_barrier with
// fine-grained vmcnt (never vmcnt(0) mid-loop).
// MODE 0: bf16 C (QKV) | MODE 2: bf16 gelu(C+bias) (FFN1)
// MODE 1: f32 C + bias (Wo, BN=64) | MODE 3: f32 C + bias + resid (FFN2, BN=64)
template <int MODE, int BN>
__global__ __launch_bounds__(256)
void gemm_bt(const bf16* __restrict__ A, const bf16* __restrict__ Bt,
             const float* __restrict__ bias, const float* __restrict__ resid,
             float* __restrict__ outF, bf16* __restrict__ outB,
             int M, int Nn, int K) {
  constexpr int NI = BN / 32;          // mfma col-tiles per wave
  __shared__ alignas(16) bf16 As[3][128 * 32];
  __shared__ alignas(16) bf16 Bs[3][BN * 32];
  const int tid = threadIdx.x;
  const int wave = tid >> 6, lane = tid & 63;
  const int m0 = blockIdx.y * 128, n0 = blockIdx.x * BN;
  const int wr = (wave >> 1) * 64, wc = (wave & 1) * (BN / 2);
  const int l15 = lane & 15, qq = lane >> 4;
  const int lr = lane >> 2, l4 = lane & 3;
  const int T = K >> 5;

  floatx4 acc[4][NI];
#pragma unroll
  for (int i = 0; i < 4; i++)
#pragma unroll
    for (int j = 0; j < NI; j++) acc[i][j] = (floatx4)0.f;

  const bf16* gA0 = A + (size_t)(m0 + wave * 16 + lr) * K + l4 * 8;
  const bf16* gA1 = gA0 + (size_t)64 * K;
  const bf16* gB0 = Bt + (size_t)(n0 + wave * 16 + lr) * K + l4 * 8;
  const bf16* gB1 = gB0 + (size_t)64 * K;
  const int lo = wave * 16 * 32;

  auto stage = [&](int t, int buf) {
    int kt = t * 32;
    load_lds16(gA0 + kt, &As[buf][lo]);
    load_lds16(gA1 + kt, &As[buf][64 * 32 + lo]);
    load_lds16(gB0 + kt, &Bs[buf][lo]);
    if (BN == 128) load_lds16(gB1 + kt, &Bs[buf][64 * 32 + lo]);
  };
  stage(0, 0);
  stage(1, 1);

  int bc = 0;
  for (int t = 0; t < T; ++t) {
    if (t < T - 1) {
      if constexpr (BN == 128)
        asm volatile("s_waitcnt vmcnt(4) lgkmcnt(0)" ::: "memory");
      else
        asm volatile("s_waitcnt vmcnt(3) lgkmcnt(0)" ::: "memory");
    } else {
      asm volatile("s_waitcnt vmcnt(0) lgkmcnt(0)" ::: "memory");
    }
    __builtin_amdgcn_s_barrier();
    if (t + 2 < T) { int bs = bc == 0 ? 2 : bc - 1; stage(t + 2, bs); }

    short8 af[4], bfr[NI];
#pragma unroll
    for (int mi = 0; mi < 4; mi++) af[mi] = ld8(&As[bc][(wr + mi * 16 + l15) * 32 + qq * 8]);
#pragma unroll
    for (int ni = 0; ni < NI; ni++) bfr[ni] = ld8(&Bs[bc][(wc + ni * 16 + l15) * 32 + qq * 8]);
#pragma unroll
    for (int mi = 0; mi < 4; mi++)
#pragma unroll
      for (int ni = 0; ni < NI; ni++)
        acc[mi][ni] = mfma16(af[mi], bfr[ni], acc[mi][ni]);
    bc = bc == 2 ? 0 : bc + 1;
  }

#pragma unroll
  for (int mi = 0; mi < 4; mi++) {
    int row = m0 + wr + mi * 16 + qq * 4;
#pragma unroll
    for (int ni = 0; ni < NI; ni++) {
      int col = n0 + wc + ni * 16 + l15;
      float bv = (MODE >= 1) ? bias[col] : 0.f;
#pragma unroll
      for (int r = 0; r < 4; r++) {
        float v = acc[mi][ni][r] + bv;
        size_t off = (size_t)(row + r) * Nn + col;
        if (MODE == 0) {
          outB[off] = __float2bfloat16(v);
        } else if (MODE == 2) {
          outB[off] = __float2bfloat16(0.5f * v * (1.f + erff(v * 0.70710678118654752f)));
        } else if (MODE == 1) {
          outF[off] = v;
        } else {
          outF[off] = v + resid[off];
        }
      }
    }
  }
}

// ---------------- flash attention v19: 32-key tiles, 32KB LDS, 4 blocks/CU ----------------
// grid (32 q-tiles, 8 heads, 4 splits) = 1024 blocks = exactly 4/CU; 256 thr.
// R5 analysis: dur pinned at ~126us across R1/R2/R5 with MfmaUtil 22% + VALUBusy 30%
// -> latency-bound at 2 waves/SIMD (LDS 64KB/block capped residency at 2 blocks/CU).
// This version halves the KV tile to 32 keys: K 8KB + V 8KB per buffer, double-buffered
// = 32KB/block -> 4 blocks/CU = 4 waves/SIMD. Per-FLOP LDS intensity unchanged (still
// 32 q-rows/wave); 32 smaller pipeline steps instead of 16.
// K=32 PV retained via permuted K staging: staged slot (ni,l15) holds key
// ni*4 + (l15>>2)*8 + (l15&3); two 16-key S^T steps fill each short8 P A-frag.
// adj bits consumed as u32 (one 32-key window per iter) to cut register state.
// VGPR budget: launch_bounds(256,4) -> cap 128 (R5 body used 124).
__global__ __launch_bounds__(256, 4)
void attn_kernel(const bf16* __restrict__ QKV, const bf16* __restrict__ Vt,
                 const uint32_t* __restrict__ adjbits32, const float* __restrict__ adj_bias,
                 bf16* __restrict__ AOpart, float* __restrict__ lpart) {
  __shared__ alignas(16) bf16 Kf[2][8 * 512];  // frag fi=ni*4+kk: permuted K rows x 32 k-dims
  __shared__ alignas(16) bf16 Vf[2][8 * 512];  // frag fi=d: V^T[d*16+l15][kt+qq*8..+7]
  const int q0 = blockIdx.x * 128;
  const int h = blockIdx.y;
  const int split = blockIdx.z;
  const int k0 = split * 1024;
  const int tid = threadIdx.x, wave = tid >> 6, lane = tid & 63;
  const int l15 = lane & 15, qq = lane >> 4;
  const float log2e = 1.4426950408889634f;
  const float beta2 = adj_bias[h] * log2e;
  const float scale2 = 0.08838834764831845f * log2e;  // 128^-0.5 * log2(e)

  // Q fragments (B-operand; 32 rows per wave)
  short8 qf[2][4];
#pragma unroll
  for (int mi = 0; mi < 2; mi++)
#pragma unroll
    for (int kk = 0; kk < 4; kk++)
      qf[mi][kk] = ld8(&QKV[(size_t)(q0 + wave * 32 + mi * 16 + l15) * 3072 +
                            h * 128 + kk * 32 + qq * 8]);

  floatx4 o[2][8];
#pragma unroll
  for (int mi = 0; mi < 2; mi++)
#pragma unroll
    for (int d = 0; d < 8; d++) o[mi][d] = (floatx4)0.f;
  float lrow[2] = {0.f, 0.f};

  // u32 adj words: word idx = qrow*128 + key/32; subtile 1 = +16 rows = +2048
  const size_t abase = (size_t)(q0 + wave * 32 + l15) * 128 + split * 32;
  // key permutation within the 32-key window (slot l15 -> key offset), +4 for ni=1
  const int kperm = ((l15 >> 2) * 8) + (l15 & 3);

  auto stage = [&](int t, int buf) {
    const int kt = k0 + t * 32;
#pragma unroll
    for (int i = 0; i < 2; i++) {
      int fi = wave * 2 + i;
      int ni = fi >> 2, kk = fi & 3;
      int krow = kt + ni * 4 + kperm;
      load_lds16(&QKV[(size_t)krow * 3072 + 1024 + h * 128 + kk * 32 + qq * 8],
                 (char*)Kf[buf] + fi * 1024);
      load_lds16(&Vt[(size_t)(h * 128 + fi * 16 + l15) * 4096 + kt + qq * 8],
                 (char*)Vf[buf] + fi * 1024);
    }
  };

  // prologue: stage tile 0, prefetch adj words for tile 0
  stage(0, 0);
  uint32_t a0c = adjbits32[abase];
  uint32_t a1c = adjbits32[abase + 2048];

  for (int t = 0; t < 32; t++) {
    // __syncthreads drains this wave's in-flight stage+adj loads and makes
    // buf[t&1] visible; all waves are also done reading buf[(t+1)&1].
    __syncthreads();
    if (t < 31) stage(t + 1, (t + 1) & 1);
    uint32_t a0n = 0, a1n = 0;
    if (t < 31) { a0n = adjbits32[abase + t + 1]; a1n = adjbits32[abase + 2048 + t + 1]; }

    const bf16* Kc = Kf[t & 1];
    const bf16* Vc = Vf[t & 1];

    // two S^T 16-key steps fill short8 P-frags, then K=32 PV over the 32-key window
    short8 pa0, pa1;
#pragma unroll
    for (int hh = 0; hh < 2; hh++) {
      floatx4 s0 = (floatx4)0.f, s1 = (floatx4)0.f;
#pragma unroll
      for (int kk = 0; kk < 4; kk++) {
        short8 kfr = ld8(&Kc[(hh * 4 + kk) * 512 + lane * 8]);
        s0 = mfma16(kfr, qf[0][kk], s0);  // D[key-slot][q] for q-subtile 0
        s1 = mfma16(kfr, qf[1][kk], s1);
      }
      // staged slot qq*4+r in step hh = window key qq*8 + hh*4 + r
      const uint32_t u0 = a0c >> (hh * 4);
      const uint32_t u1 = a1c >> (hh * 4);
      const int bp = qq * 8;
      float p0, p1, p2, p3;
      p0 = __builtin_amdgcn_exp2f(fmaf(s0[0], scale2, ((u0 >> (bp + 0)) & 1) ? beta2 : 0.f));
      p1 = __builtin_amdgcn_exp2f(fmaf(s0[1], scale2, ((u0 >> (bp + 1)) & 1) ? beta2 : 0.f));
      p2 = __builtin_amdgcn_exp2f(fmaf(s0[2], scale2, ((u0 >> (bp + 2)) & 1) ? beta2 : 0.f));
      p3 = __builtin_amdgcn_exp2f(fmaf(s0[3], scale2, ((u0 >> (bp + 3)) & 1) ? beta2 : 0.f));
      lrow[0] += (p0 + p1) + (p2 + p3);
      pa0[hh * 4 + 0] = bfb(p0); pa0[hh * 4 + 1] = bfb(p1);
      pa0[hh * 4 + 2] = bfb(p2); pa0[hh * 4 + 3] = bfb(p3);
      p0 = __builtin_amdgcn_exp2f(fmaf(s1[0], scale2, ((u1 >> (bp + 0)) & 1) ? beta2 : 0.f));
      p1 = __builtin_amdgcn_exp2f(fmaf(s1[1], scale2, ((u1 >> (bp + 1)) & 1) ? beta2 : 0.f));
      p2 = __builtin_amdgcn_exp2f(fmaf(s1[2], scale2, ((u1 >> (bp + 2)) & 1) ? beta2 : 0.f));
      p3 = __builtin_amdgcn_exp2f(fmaf(s1[3], scale2, ((u1 >> (bp + 3)) & 1) ? beta2 : 0.f));
      lrow[1] += (p0 + p1) + (p2 + p3);
      pa1[hh * 4 + 0] = bfb(p0); pa1[hh * 4 + 1] = bfb(p1);
      pa1[hh * 4 + 2] = bfb(p2); pa1[hh * 4 + 3] = bfb(p3);
    }
    // PV, K=32: B-frag = V[window key qq*8+j][d*16+l15] = one b128 from Vf
#pragma unroll
    for (int d = 0; d < 8; d++) {
      short8 vf8 = ld8(&Vc[d * 512 + lane * 8]);
      o[0][d] = mfma16(pa0, vf8, o[0][d]);
      o[1][d] = mfma16(pa1, vf8, o[1][d]);
    }
    a0c = a0n; a1c = a1n;
  }

  // epilogue: reduce lrow over quads; write bf16 partials (additive across splits)
#pragma unroll
  for (int mi = 0; mi < 2; mi++) {
    float v = lrow[mi];
    v += __shfl_xor(v, 16, 64);
    v += __shfl_xor(v, 32, 64);
    if (qq == 0) lpart[((size_t)split * 4096 + q0 + wave * 32 + mi * 16 + l15) * 8 + h] = v;
#pragma unroll
    for (int r = 0; r < 4; r++) {
      int grow = q0 + wave * 32 + mi * 16 + qq * 4 + r;
      bf16* dst = AOpart + ((size_t)split * 4096 + grow) * 1024 + h * 128;
#pragma unroll
      for (int d = 0; d < 8; d++) dst[d * 16 + l15] = __float2bfloat16(o[mi][d][r]);
    }
  }
}

// ---------------- combine split-K partials, normalize -> bf16 AO ----------------
__global__ __launch_bounds__(256)
void attn_norm(const bf16* __restrict__ AOpart, const float* __restrict__ lpart,
               bf16* __restrict__ AO) {
  int row = blockIdx.x, tid = threadIdx.x;
  int h = tid >> 5;
  float ls = 0.f;
#pragma unroll
  for (int s = 0; s < 4; s++) ls += lpart[((size_t)s * 4096 + row) * 8 + h];
  float a0 = 0.f, a1 = 0.f, a2 = 0.f, a3 = 0.f;
#pragma unroll
  for (int s = 0; s < 4; s++) {
    short4v v = *(const short4v*)&AOpart[((size_t)s * 4096 + row) * 1024 + tid * 4];
    a0 += fbf(v.x); a1 += fbf(v.y); a2 += fbf(v.z); a3 += fbf(v.w);
  }
  float inv = 1.f / ls;
  bf16* op = AO + (size_t)row * 1024 + tid * 4;
  op[0] = __float2bfloat16(a0 * inv);
  op[1] = __float2bfloat16(a1 * inv);
  op[2] = __float2bfloat16(a2 * inv);
  op[3] = __float2bfloat16(a3 * inv);
}

// ---------------- fused double-LayerNorm ----------------
DEVI void block_sum2(float& a, float& b, float* red) {
#pragma unroll
  for (int o = 1; o < 64; o <<= 1) { a += __shfl_xor(a, o, 64); b += __shfl_xor(b, o, 64); }
  int wv = threadIdx.x >> 6;
  if ((threadIdx.x & 63) == 0) { red[wv] = a; red[4 + wv] = b; }
  __syncthreads();
  a = red[0] + red[1] + red[2] + red[3];
  b = red[4] + red[5] + red[6] + red[7];
  __syncthreads();
}

__global__ __launch_bounds__(256)
void ln2_kernel(const float* __restrict__ x, const float* __restrict__ ao,
                const float* __restrict__ g1, const float* __restrict__ b1,
                const float* __restrict__ g2, const float* __restrict__ b2,
                float* __restrict__ hout, bf16* __restrict__ fln) {
  __shared__ float red[8];
  const int row = blockIdx.x, tid = threadIdx.x;
  float4 xv = ((const float4*)(x + (size_t)row * 1024))[tid];
  float4 av = ((const float4*)(ao + (size_t)row * 1024))[tid];
  float s0 = xv.x + av.x, s1 = xv.y + av.y, s2 = xv.z + av.z, s3 = xv.w + av.w;
  float sum = s0 + s1 + s2 + s3;
  float ssq = s0 * s0 + s1 * s1 + s2 * s2 + s3 * s3;
  block_sum2(sum, ssq, red);
  float mu = sum * (1.f / 1024.f);
  float rs = rsqrtf(ssq * (1.f / 1024.f) - mu * mu + 1e-5f);
  float4 gv = ((const float4*)g1)[tid], bv = ((const float4*)b1)[tid];
  float h0 = (s0 - mu) * rs * gv.x + bv.x;
  float h1 = (s1 - mu) * rs * gv.y + bv.y;
  float h2 = (s2 - mu) * rs * gv.z + bv.z;
  float h3 = (s3 - mu) * rs * gv.w + bv.w;
  float4 hv; hv.x = h0; hv.y = h1; hv.z = h2; hv.w = h3;
  ((float4*)(hout + (size_t)row * 1024))[tid] = hv;
  float sum2 = h0 + h1 + h2 + h3;
  float ssq2 = h0 * h0 + h1 * h1 + h2 * h2 + h3 * h3;
  block_sum2(sum2, ssq2, red);
  float mu2 = sum2 * (1.f / 1024.f);
  float rs2 = rsqrtf(ssq2 * (1.f / 1024.f) - mu2 * mu2 + 1e-5f);
  float4 g2v = ((const float4*)g2)[tid], b2v = ((const float4*)b2)[tid];
  bf16* op = fln + (size_t)row * 1024 + tid * 4;
  op[0] = __float2bfloat16((h0 - mu2) * rs2 * g2v.x + b2v.x);
  op[1] = __float2bfloat16((h1 - mu2) * rs2 * g2v.y + b2v.y);
  op[2] = __float2bfloat16((h2 - mu2) * rs2 * g2v.z + b2v.z);
  op[3] = __float2bfloat16((h3 - mu2) * rs2 * g2v.w + b2v.w);
}

// ---------------- host launch ----------------
extern "C" void kernel_launch(void* const* d_in, const int* in_sizes, int n_in,
                              void* d_out, int out_size, void* d_ws, size_t ws_size,
                              hipStream_t stream) {
  const float* x    = (const float*)d_in[0];
  const float* adj  = (const float*)d_in[1];
  const float* Wq   = (const float*)d_in[2];
  const float* Wk   = (const float*)d_in[3];
  const float* Wv   = (const float*)d_in[4];
  const float* Wo   = (const float*)d_in[5];
  const float* Wob  = (const float*)d_in[6];
  const float* adjb = (const float*)d_in[7];
  const float* g1   = (const float*)d_in[8];
  const float* b1   = (const float*)d_in[9];
  const float* g2   = (const float*)d_in[10];
  const float* b2   = (const float*)d_in[11];
  const float* W1   = (const float*)d_in[12];
  const float* fb1  = (const float*)d_in[13];
  const float* W2   = (const float*)d_in[14];
  const float* fb2  = (const float*)d_in[15];
  float* out = (float*)d_out;

  char* w = (char*)d_ws;
  size_t off = 0;
  auto take = [&](size_t bytes) {
    char* p = w + off;
    off += (bytes + 255) & ~(size_t)255;
    return p;
  };
  bf16* xb    = (bf16*)take(4096ull * 1024 * 2);
  bf16* Wqkvt = (bf16*)take(3072ull * 1024 * 2);
  bf16* Wot   = (bf16*)take(1024ull * 1024 * 2);
  bf16* W1t   = (bf16*)take(2048ull * 1024 * 2);
  bf16* W2t   = (bf16*)take(1024ull * 2048 * 2);
  bf16* QKV   = (bf16*)take(4096ull * 3072 * 2);
  bf16* Vt    = (bf16*)take(1024ull * 4096 * 2);
  bf16* AO    = (bf16*)take(4096ull * 1024 * 2);
  u64*  adjbits = (u64*)take(4096ull * 64 * 8);
  float* lpart  = (float*)take(4ull * 4096 * 8 * 4);
  // 32MB region reused over time: AOpart (until attn_norm) -> WoP (after)
  char* big = take(32ull << 20);
  bf16*  AOpart = (bf16*)big;                       // 4 x 8MB bf16
  float* WoP    = (float*)big;                      // 16MB f32
  float* H   = (float*)take(4096ull * 1024 * 4);
  bf16*  FLN = (bf16*)take(4096ull * 1024 * 2);
  bf16*  G   = (bf16*)take(4096ull * 2048 * 2);

  dim3 tb(32, 8);
  // fused: x cvt + adj bits + all weight transposes (12288 blocks total)
  prep_all<<<12288, 256, 0, stream>>>(x, xb, adj, adjbits, Wq, Wk, Wv, Wo, W1, W2,
                                      Wqkvt, Wot, W1t, W2t);
  // QKV = xb @ [Wq|Wk|Wv]   (bf16 out)
  gemm_bt<0, 128><<<dim3(24, 32), 256, 0, stream>>>(xb, Wqkvt, nullptr, nullptr,
                                                    nullptr, QKV, 4096, 3072, 1024);
  // plain V^T per head: Vt[h*128+dh][n]
  tr_bf16t<<<dim3(32, 128), tb, 0, stream>>>(QKV + 2048, Vt, 3072);
  // flash attention, split-K x4, 32-key tiles, 4 blocks/CU
  attn_kernel<<<dim3(32, 8, 4), 256, 0, stream>>>(QKV, Vt, (const uint32_t*)adjbits,
                                                  adjb, AOpart, lpart);
  attn_norm<<<4096, 256, 0, stream>>>(AOpart, lpart, AO);
  // WoP = AO @ Wo + Wo_b   (f32 out; 128x64 tiles -> 512 blocks, no split-K)
  gemm_bt<1, 64><<<dim3(16, 32), 256, 0, stream>>>(AO, Wot, Wob, nullptr,
                                                   WoP, nullptr, 4096, 1024, 1024);
  // h = LN(x + WoP); FLN = bf16(LN(h))
  ln2_kernel<<<4096, 256, 0, stream>>>(x, WoP, g1, b1, g2, b2, H, FLN);
  // G = gelu(FLN @ W1 + b1)   (bf16 out)
  gemm_bt<2, 128><<<dim3(16, 32), 256, 0, stream>>>(FLN, W1t, fb1, nullptr,
                                                    nullptr, G, 4096, 2048, 1024);
  // out = G @ W2 + b2 + h   (f32 out; 128x64 tiles -> 512 blocks, no split-K)
  gemm_bt<3, 64><<<dim3(16, 32), 256, 0, stream>>>(G, W2t, fb2, H,
                                                   out, nullptr, 4096, 1024, 2048);
}

// Round 7
// 422.179 us; speedup vs baseline: 1.3316x; 1.3316x over previous
//
#include <hip/hip_runtime.h>
#include <hip/hip_bf16.h>
#include <cstdint>
#include <cstddef>

typedef __hip_bfloat16 bf16;
typedef __attribute__((ext_vector_type(8))) short short8;
typedef __attribute__((ext_vector_type(4))) short short4v;
typedef __attribute__((ext_vector_type(4))) float floatx4;
typedef unsigned long long u64;

#define DEVI static __device__ __forceinline__

DEVI void load_lds16(const void* g, void* l) {
  __builtin_amdgcn_global_load_lds((const __attribute__((address_space(1))) unsigned int*)g,
                                   (__attribute__((address_space(3))) unsigned int*)l, 16, 0, 0);
}
DEVI short8 ld8(const bf16* p) { return *(const short8*)p; }
DEVI floatx4 mfma16(short8 a, short8 b, floatx4 c) {
  return __builtin_amdgcn_mfma_f32_16x16x32_bf16(a, b, c, 0, 0, 0);
}
DEVI short bfb(float f) { bf16 h = __float2bfloat16(f); return __builtin_bit_cast(short, h); }
DEVI float fbf(short s) { bf16 h = __builtin_bit_cast(bf16, s); return __bfloat162float(h); }

// ---------------- fused prep: x->bf16 + adj bits + all 6 weight transposes ----------------
// Block budget: 4096 (x/adj) + 4096 (Wq,Wk,Wv,Wo) + 2048 (W1) + 2048 (W2) = 12288.
DEVI void tr_tile(const float* in, bf16* out, int R, int C, int bx, int by) {
  __shared__ float t[32][33];
  int c0 = bx * 32, r0 = by * 32;
  int tx = threadIdx.x & 31, ty = threadIdx.x >> 5;
#pragma unroll
  for (int i = 0; i < 32; i += 8) t[ty + i][tx] = in[(size_t)(r0 + ty + i) * C + c0 + tx];
  __syncthreads();
#pragma unroll
  for (int i = 0; i < 32; i += 8)
    out[(size_t)(c0 + ty + i) * R + r0 + tx] = __float2bfloat16(t[tx][ty + i]);
}

__global__ __launch_bounds__(256)
void prep_all(const float* __restrict__ x, bf16* __restrict__ xb,
              const float* __restrict__ adj, u64* __restrict__ bits,
              const float* Wq, const float* Wk, const float* Wv, const float* Wo,
              const float* W1, const float* W2,
              bf16* Wqkvt, bf16* Wot, bf16* W1t, bf16* W2t) {
  int id = blockIdx.x;
  if (id < 4096) {
    const int row = id, tid = threadIdx.x;
    const int wave = tid >> 6, lane = tid & 63;
    float4 v = ((const float4*)(x + (size_t)row * 1024))[tid];
    bf16* o = xb + (size_t)row * 1024 + tid * 4;
    o[0] = __float2bfloat16(v.x); o[1] = __float2bfloat16(v.y);
    o[2] = __float2bfloat16(v.z); o[3] = __float2bfloat16(v.w);
    const float* arow = adj + (size_t)row * 4096;
#pragma unroll
    for (int it = 0; it < 16; it++) {
      int col = it * 256 + tid;
      u64 m = __ballot(arow[col] != 0.f);
      if (lane == 0) bits[(size_t)row * 64 + it * 4 + wave] = m;
    }
  } else if (id < 8192) {
    int q = id - 4096, w = q >> 10, t = q & 1023;
    const float* in = w == 0 ? Wq : w == 1 ? Wk : w == 2 ? Wv : Wo;
    bf16* out = w == 0 ? Wqkvt : w == 1 ? Wqkvt + 1024ull * 1024
              : w == 2 ? Wqkvt + 2048ull * 1024 : Wot;
    tr_tile(in, out, 1024, 1024, t & 31, t >> 5);
  } else if (id < 10240) {
    int t = id - 8192;
    tr_tile(W1, W1t, 1024, 2048, t & 63, t >> 6);
  } else {
    int t = id - 10240;
    tr_tile(W2, W2t, 2048, 1024, t & 31, t >> 5);
  }
}

// ---------------- plain V^T build: out[dh][n] = V[n][dh] ----------------
__global__ __launch_bounds__(256)
void tr_bf16t(const bf16* __restrict__ in, bf16* __restrict__ out, int inLd) {
  __shared__ bf16 t[32][33];
  int c0 = blockIdx.x * 32, r0 = blockIdx.y * 32;
  int tx = threadIdx.x, ty = threadIdx.y;
#pragma unroll
  for (int i = 0; i < 32; i += 8) t[ty + i][tx] = in[(size_t)(r0 + ty + i) * inLd + c0 + tx];
  __syncthreads();
#pragma unroll
  for (int i = 0; i < 32; i += 8)
    out[(size_t)(c0 + ty + i) * 4096 + r0 + tx] = t[tx][ty + i];
}

// ---------------- bf16 GEMM, C = A[M][K] @ Bt[N][K]^T, tile 128 x BN ----------------
// Pipelined K-loop: 3 LDS buffers, loads 2 tiles in flight, raw s_barrier with
// fine-grained vmcnt (never vmcnt(0) mid-loop).
// MODE 0: bf16 C (QKV) | MODE 2: bf16 gelu(C+bias) (FFN1)
// MODE 1: f32 C + bias (Wo, BN=64) | MODE 3: f32 C + bias + resid (FFN2, BN=64)
template <int MODE, int BN>
__global__ __launch_bounds__(256)
void gemm_bt(const bf16* __restrict__ A, const bf16* __restrict__ Bt,
             const float* __restrict__ bias, const float* __restrict__ resid,
             float* __restrict__ outF, bf16* __restrict__ outB,
             int M, int Nn, int K) {
  constexpr int NI = BN / 32;          // mfma col-tiles per wave
  __shared__ alignas(16) bf16 As[3][128 * 32];
  __shared__ alignas(16) bf16 Bs[3][BN * 32];
  const int tid = threadIdx.x;
  const int wave = tid >> 6, lane = tid & 63;
  const int m0 = blockIdx.y * 128, n0 = blockIdx.x * BN;
  const int wr = (wave >> 1) * 64, wc = (wave & 1) * (BN / 2);
  const int l15 = lane & 15, qq = lane >> 4;
  const int lr = lane >> 2, l4 = lane & 3;
  const int T = K >> 5;

  floatx4 acc[4][NI];
#pragma unroll
  for (int i = 0; i < 4; i++)
#pragma unroll
    for (int j = 0; j < NI; j++) acc[i][j] = (floatx4)0.f;

  const bf16* gA0 = A + (size_t)(m0 + wave * 16 + lr) * K + l4 * 8;
  const bf16* gA1 = gA0 + (size_t)64 * K;
  const bf16* gB0 = Bt + (size_t)(n0 + wave * 16 + lr) * K + l4 * 8;
  const bf16* gB1 = gB0 + (size_t)64 * K;
  const int lo = wave * 16 * 32;

  auto stage = [&](int t, int buf) {
    int kt = t * 32;
    load_lds16(gA0 + kt, &As[buf][lo]);
    load_lds16(gA1 + kt, &As[buf][64 * 32 + lo]);
    load_lds16(gB0 + kt, &Bs[buf][lo]);
    if (BN == 128) load_lds16(gB1 + kt, &Bs[buf][64 * 32 + lo]);
  };
  stage(0, 0);
  stage(1, 1);

  int bc = 0;
  for (int t = 0; t < T; ++t) {
    if (t < T - 1) {
      if constexpr (BN == 128)
        asm volatile("s_waitcnt vmcnt(4) lgkmcnt(0)" ::: "memory");
      else
        asm volatile("s_waitcnt vmcnt(3) lgkmcnt(0)" ::: "memory");
    } else {
      asm volatile("s_waitcnt vmcnt(0) lgkmcnt(0)" ::: "memory");
    }
    __builtin_amdgcn_s_barrier();
    if (t + 2 < T) { int bs = bc == 0 ? 2 : bc - 1; stage(t + 2, bs); }

    short8 af[4], bfr[NI];
#pragma unroll
    for (int mi = 0; mi < 4; mi++) af[mi] = ld8(&As[bc][(wr + mi * 16 + l15) * 32 + qq * 8]);
#pragma unroll
    for (int ni = 0; ni < NI; ni++) bfr[ni] = ld8(&Bs[bc][(wc + ni * 16 + l15) * 32 + qq * 8]);
#pragma unroll
    for (int mi = 0; mi < 4; mi++)
#pragma unroll
      for (int ni = 0; ni < NI; ni++)
        acc[mi][ni] = mfma16(af[mi], bfr[ni], acc[mi][ni]);
    bc = bc == 2 ? 0 : bc + 1;
  }

#pragma unroll
  for (int mi = 0; mi < 4; mi++) {
    int row = m0 + wr + mi * 16 + qq * 4;
#pragma unroll
    for (int ni = 0; ni < NI; ni++) {
      int col = n0 + wc + ni * 16 + l15;
      float bv = (MODE >= 1) ? bias[col] : 0.f;
#pragma unroll
      for (int r = 0; r < 4; r++) {
        float v = acc[mi][ni][r] + bv;
        size_t off = (size_t)(row + r) * Nn + col;
        if (MODE == 0) {
          outB[off] = __float2bfloat16(v);
        } else if (MODE == 2) {
          outB[off] = __float2bfloat16(0.5f * v * (1.f + erff(v * 0.70710678118654752f)));
        } else if (MODE == 1) {
          outF[off] = v;
        } else {
          outF[off] = v + resid[off];
        }
      }
    }
  }
}

// ---------------- flash attention v20: R5 base + latency-hiding schedule ----------------
// grid (32 q-tiles, 8 heads, 4 splits); 256 thr; LDS 64KB; launch_bounds(256,2).
// Register model (R3/R6 lesson): reported VGPR excludes the 64 accumulator AGPRs;
// total budget = 512 / waves-per-EU. At (256,2): 256/wave total; R5 used ~188 ->
// ~68 regs of FREE headroom at unchanged occupancy (2 waves/SIMD, one per block ->
// the two waves on a SIMD are from INDEPENDENT blocks).
// This version spends that headroom on latency hiding:
//  (a) per-window V-frag register prefetch (8 x b128) issued BEFORE QK -> PV never
//      stalls on lgkmcnt;
//  (b) all 4 QK chains (both hh steps) computed before softmax -> 4 independent
//      MFMA dep-chains instead of 2, halving exposed MFMA latency;
//  (c) s_setprio(1) around MFMA clusters (T5): inter-block wave arbitration.
// Data layout identical to R5 (K=32 PV via permuted K staging, K/V double-buffered).
__global__ __launch_bounds__(256, 2)
void attn_kernel(const bf16* __restrict__ QKV, const bf16* __restrict__ Vt,
                 const u64* __restrict__ adjbits, const float* __restrict__ adj_bias,
                 bf16* __restrict__ AOpart, float* __restrict__ lpart) {
  __shared__ alignas(16) bf16 Kf[2][16 * 512];  // frag fi=ni*4+kk: permuted K rows x 32 k-dims
  __shared__ alignas(16) bf16 Vf[2][16 * 512];  // frag fi=d*2+k2:  V^T[d*16+l15][kt+k2*32+..]
  const int q0 = blockIdx.x * 128;
  const int h = blockIdx.y;
  const int split = blockIdx.z;
  const int k0 = split * 1024;
  const int tid = threadIdx.x, wave = tid >> 6, lane = tid & 63;
  const int l15 = lane & 15, qq = lane >> 4;
  const float log2e = 1.4426950408889634f;
  const float beta2 = adj_bias[h] * log2e;
  const float scale2 = 0.08838834764831845f * log2e;  // 128^-0.5 * log2(e)

  // Q fragments (B-operand; 32 rows per wave)
  short8 qf[2][4];
#pragma unroll
  for (int mi = 0; mi < 2; mi++)
#pragma unroll
    for (int kk = 0; kk < 4; kk++)
      qf[mi][kk] = ld8(&QKV[(size_t)(q0 + wave * 32 + mi * 16 + l15) * 3072 +
                            h * 128 + kk * 32 + qq * 8]);

  floatx4 o[2][8];
#pragma unroll
  for (int mi = 0; mi < 2; mi++)
#pragma unroll
    for (int d = 0; d < 8; d++) o[mi][d] = (floatx4)0.f;
  float lrow[2] = {0.f, 0.f};

  const size_t abase = (size_t)(q0 + wave * 32 + l15) * 64 + split * 16;
  // key permutation within a 32-key window (slot l15 -> key offset), +4 for odd ni
  const int kperm = ((l15 >> 2) * 8) + (l15 & 3);

  auto stage = [&](int t, int buf) {
    const int kt = k0 + t * 64;
#pragma unroll
    for (int i = 0; i < 4; i++) {
      int fi = wave * 4 + i;
      int ni = fi >> 2, kk = fi & 3;
      int krow = kt + (ni >> 1) * 32 + (ni & 1) * 4 + kperm;
      load_lds16(&QKV[(size_t)krow * 3072 + 1024 + h * 128 + kk * 32 + qq * 8],
                 (char*)Kf[buf] + fi * 1024);
      int d = fi >> 1, k2 = fi & 1;
      load_lds16(&Vt[(size_t)(h * 128 + d * 16 + l15) * 4096 + kt + k2 * 32 + qq * 8],
                 (char*)Vf[buf] + fi * 1024);
    }
  };

  // prologue: stage tile 0, prefetch adj words for tile 0
  stage(0, 0);
  u64 a0c = adjbits[abase];
  u64 a1c = adjbits[abase + 1024];

  for (int t = 0; t < 16; t++) {
    // __syncthreads drains this wave's in-flight stage+adj loads and makes
    // buf[t&1] visible; all waves are also done reading buf[(t+1)&1].
    __syncthreads();
    if (t < 15) stage(t + 1, (t + 1) & 1);
    u64 a0n = 0, a1n = 0;
    if (t < 15) { a0n = adjbits[abase + t + 1]; a1n = adjbits[abase + 1024 + t + 1]; }

    const bf16* Kc = Kf[t & 1];
    const bf16* Vc = Vf[t & 1];
    const uint32_t w0lo = (uint32_t)a0c, w0hi = (uint32_t)(a0c >> 32);
    const uint32_t w1lo = (uint32_t)a1c, w1hi = (uint32_t)(a1c >> 32);

    // per 32-key window: V reg-prefetch, then 4-chain QK, softmax, K=32 PV
#pragma unroll
    for (int ni2 = 0; ni2 < 2; ni2++) {
      // (a) V-frag register prefetch: issued first so PV never waits on LDS
      short8 vreg[8];
#pragma unroll
      for (int d = 0; d < 8; d++)
        vreg[d] = ld8((const bf16*)((const char*)Vc + (d * 2 + ni2) * 1024 +
                                    qq * 256 + l15 * 16));
      // (b) both hh steps' QK as 4 independent MFMA chains
      floatx4 s00 = (floatx4)0.f, s10 = (floatx4)0.f;  // hh=0: subtile 0,1
      floatx4 s01 = (floatx4)0.f, s11 = (floatx4)0.f;  // hh=1: subtile 0,1
      __builtin_amdgcn_s_setprio(1);
#pragma unroll
      for (int kk = 0; kk < 4; kk++) {
        short8 kfr0 = ld8(&Kc[((ni2 * 2 + 0) * 4 + kk) * 512 + lane * 8]);
        s00 = mfma16(kfr0, qf[0][kk], s00);
        s10 = mfma16(kfr0, qf[1][kk], s10);
      }
#pragma unroll
      for (int kk = 0; kk < 4; kk++) {
        short8 kfr1 = ld8(&Kc[((ni2 * 2 + 1) * 4 + kk) * 512 + lane * 8]);
        s01 = mfma16(kfr1, qf[0][kk], s01);
        s11 = mfma16(kfr1, qf[1][kk], s11);
      }
      __builtin_amdgcn_s_setprio(0);
      // softmax both hh steps -> short8 P A-frags
      short8 pa0, pa1;
      {
        const int bp = qq * 8;
        // hh = 0
        uint32_t u0 = (ni2 ? w0hi : w0lo);
        uint32_t u1 = (ni2 ? w1hi : w1lo);
        float p0, p1, p2, p3;
        p0 = __builtin_amdgcn_exp2f(fmaf(s00[0], scale2, ((u0 >> (bp + 0)) & 1) ? beta2 : 0.f));
        p1 = __builtin_amdgcn_exp2f(fmaf(s00[1], scale2, ((u0 >> (bp + 1)) & 1) ? beta2 : 0.f));
        p2 = __builtin_amdgcn_exp2f(fmaf(s00[2], scale2, ((u0 >> (bp + 2)) & 1) ? beta2 : 0.f));
        p3 = __builtin_amdgcn_exp2f(fmaf(s00[3], scale2, ((u0 >> (bp + 3)) & 1) ? beta2 : 0.f));
        lrow[0] += (p0 + p1) + (p2 + p3);
        pa0[0] = bfb(p0); pa0[1] = bfb(p1); pa0[2] = bfb(p2); pa0[3] = bfb(p3);
        p0 = __builtin_amdgcn_exp2f(fmaf(s10[0], scale2, ((u1 >> (bp + 0)) & 1) ? beta2 : 0.f));
        p1 = __builtin_amdgcn_exp2f(fmaf(s10[1], scale2, ((u1 >> (bp + 1)) & 1) ? beta2 : 0.f));
        p2 = __builtin_amdgcn_exp2f(fmaf(s10[2], scale2, ((u1 >> (bp + 2)) & 1) ? beta2 : 0.f));
        p3 = __builtin_amdgcn_exp2f(fmaf(s10[3], scale2, ((u1 >> (bp + 3)) & 1) ? beta2 : 0.f));
        lrow[1] += (p0 + p1) + (p2 + p3);
        pa1[0] = bfb(p0); pa1[1] = bfb(p1); pa1[2] = bfb(p2); pa1[3] = bfb(p3);
        // hh = 1 (bits shifted by 4)
        u0 >>= 4; u1 >>= 4;
        p0 = __builtin_amdgcn_exp2f(fmaf(s01[0], scale2, ((u0 >> (bp + 0)) & 1) ? beta2 : 0.f));
        p1 = __builtin_amdgcn_exp2f(fmaf(s01[1], scale2, ((u0 >> (bp + 1)) & 1) ? beta2 : 0.f));
        p2 = __builtin_amdgcn_exp2f(fmaf(s01[2], scale2, ((u0 >> (bp + 2)) & 1) ? beta2 : 0.f));
        p3 = __builtin_amdgcn_exp2f(fmaf(s01[3], scale2, ((u0 >> (bp + 3)) & 1) ? beta2 : 0.f));
        lrow[0] += (p0 + p1) + (p2 + p3);
        pa0[4] = bfb(p0); pa0[5] = bfb(p1); pa0[6] = bfb(p2); pa0[7] = bfb(p3);
        p0 = __builtin_amdgcn_exp2f(fmaf(s11[0], scale2, ((u1 >> (bp + 0)) & 1) ? beta2 : 0.f));
        p1 = __builtin_amdgcn_exp2f(fmaf(s11[1], scale2, ((u1 >> (bp + 1)) & 1) ? beta2 : 0.f));
        p2 = __builtin_amdgcn_exp2f(fmaf(s11[2], scale2, ((u1 >> (bp + 2)) & 1) ? beta2 : 0.f));
        p3 = __builtin_amdgcn_exp2f(fmaf(s11[3], scale2, ((u1 >> (bp + 3)) & 1) ? beta2 : 0.f));
        lrow[1] += (p0 + p1) + (p2 + p3);
        pa1[4] = bfb(p0); pa1[5] = bfb(p1); pa1[6] = bfb(p2); pa1[7] = bfb(p3);
      }
      // (c) PV, K=32, from registers only
      __builtin_amdgcn_s_setprio(1);
#pragma unroll
      for (int d = 0; d < 8; d++) {
        o[0][d] = mfma16(pa0, vreg[d], o[0][d]);
        o[1][d] = mfma16(pa1, vreg[d], o[1][d]);
      }
      __builtin_amdgcn_s_setprio(0);
    }
    a0c = a0n; a1c = a1n;
  }

  // epilogue: reduce lrow over quads; write bf16 partials (additive across splits)
#pragma unroll
  for (int mi = 0; mi < 2; mi++) {
    float v = lrow[mi];
    v += __shfl_xor(v, 16, 64);
    v += __shfl_xor(v, 32, 64);
    if (qq == 0) lpart[((size_t)split * 4096 + q0 + wave * 32 + mi * 16 + l15) * 8 + h] = v;
#pragma unroll
    for (int r = 0; r < 4; r++) {
      int grow = q0 + wave * 32 + mi * 16 + qq * 4 + r;
      bf16* dst = AOpart + ((size_t)split * 4096 + grow) * 1024 + h * 128;
#pragma unroll
      for (int d = 0; d < 8; d++) dst[d * 16 + l15] = __float2bfloat16(o[mi][d][r]);
    }
  }
}

// ---------------- combine split-K partials, normalize -> bf16 AO ----------------
__global__ __launch_bounds__(256)
void attn_norm(const bf16* __restrict__ AOpart, const float* __restrict__ lpart,
               bf16* __restrict__ AO) {
  int row = blockIdx.x, tid = threadIdx.x;
  int h = tid >> 5;
  float ls = 0.f;
#pragma unroll
  for (int s = 0; s < 4; s++) ls += lpart[((size_t)s * 4096 + row) * 8 + h];
  float a0 = 0.f, a1 = 0.f, a2 = 0.f, a3 = 0.f;
#pragma unroll
  for (int s = 0; s < 4; s++) {
    short4v v = *(const short4v*)&AOpart[((size_t)s * 4096 + row) * 1024 + tid * 4];
    a0 += fbf(v.x); a1 += fbf(v.y); a2 += fbf(v.z); a3 += fbf(v.w);
  }
  float inv = 1.f / ls;
  bf16* op = AO + (size_t)row * 1024 + tid * 4;
  op[0] = __float2bfloat16(a0 * inv);
  op[1] = __float2bfloat16(a1 * inv);
  op[2] = __float2bfloat16(a2 * inv);
  op[3] = __float2bfloat16(a3 * inv);
}

// ---------------- fused double-LayerNorm ----------------
DEVI void block_sum2(float& a, float& b, float* red) {
#pragma unroll
  for (int o = 1; o < 64; o <<= 1) { a += __shfl_xor(a, o, 64); b += __shfl_xor(b, o, 64); }
  int wv = threadIdx.x >> 6;
  if ((threadIdx.x & 63) == 0) { red[wv] = a; red[4 + wv] = b; }
  __syncthreads();
  a = red[0] + red[1] + red[2] + red[3];
  b = red[4] + red[5] + red[6] + red[7];
  __syncthreads();
}

__global__ __launch_bounds__(256)
void ln2_kernel(const float* __restrict__ x, const float* __restrict__ ao,
                const float* __restrict__ g1, const float* __restrict__ b1,
                const float* __restrict__ g2, const float* __restrict__ b2,
                float* __restrict__ hout, bf16* __restrict__ fln) {
  __shared__ float red[8];
  const int row = blockIdx.x, tid = threadIdx.x;
  float4 xv = ((const float4*)(x + (size_t)row * 1024))[tid];
  float4 av = ((const float4*)(ao + (size_t)row * 1024))[tid];
  float s0 = xv.x + av.x, s1 = xv.y + av.y, s2 = xv.z + av.z, s3 = xv.w + av.w;
  float sum = s0 + s1 + s2 + s3;
  float ssq = s0 * s0 + s1 * s1 + s2 * s2 + s3 * s3;
  block_sum2(sum, ssq, red);
  float mu = sum * (1.f / 1024.f);
  float rs = rsqrtf(ssq * (1.f / 1024.f) - mu * mu + 1e-5f);
  float4 gv = ((const float4*)g1)[tid], bv = ((const float4*)b1)[tid];
  float h0 = (s0 - mu) * rs * gv.x + bv.x;
  float h1 = (s1 - mu) * rs * gv.y + bv.y;
  float h2 = (s2 - mu) * rs * gv.z + bv.z;
  float h3 = (s3 - mu) * rs * gv.w + bv.w;
  float4 hv; hv.x = h0; hv.y = h1; hv.z = h2; hv.w = h3;
  ((float4*)(hout + (size_t)row * 1024))[tid] = hv;
  float sum2 = h0 + h1 + h2 + h3;
  float ssq2 = h0 * h0 + h1 * h1 + h2 * h2 + h3 * h3;
  block_sum2(sum2, ssq2, red);
  float mu2 = sum2 * (1.f / 1024.f);
  float rs2 = rsqrtf(ssq2 * (1.f / 1024.f) - mu2 * mu2 + 1e-5f);
  float4 g2v = ((const float4*)g2)[tid], b2v = ((const float4*)b2)[tid];
  bf16* op = fln + (size_t)row * 1024 + tid * 4;
  op[0] = __float2bfloat16((h0 - mu2) * rs2 * g2v.x + b2v.x);
  op[1] = __float2bfloat16((h1 - mu2) * rs2 * g2v.y + b2v.y);
  op[2] = __float2bfloat16((h2 - mu2) * rs2 * g2v.z + b2v.z);
  op[3] = __float2bfloat16((h3 - mu2) * rs2 * g2v.w + b2v.w);
}

// ---------------- host launch ----------------
extern "C" void kernel_launch(void* const* d_in, const int* in_sizes, int n_in,
                              void* d_out, int out_size, void* d_ws, size_t ws_size,
                              hipStream_t stream) {
  const float* x    = (const float*)d_in[0];
  const float* adj  = (const float*)d_in[1];
  const float* Wq   = (const float*)d_in[2];
  const float* Wk   = (const float*)d_in[3];
  const float* Wv   = (const float*)d_in[4];
  const float* Wo   = (const float*)d_in[5];
  const float* Wob  = (const float*)d_in[6];
  const float* adjb = (const float*)d_in[7];
  const float* g1   = (const float*)d_in[8];
  const float* b1   = (const float*)d_in[9];
  const float* g2   = (const float*)d_in[10];
  const float* b2   = (const float*)d_in[11];
  const float* W1   = (const float*)d_in[12];
  const float* fb1  = (const float*)d_in[13];
  const float* W2   = (const float*)d_in[14];
  const float* fb2  = (const float*)d_in[15];
  float* out = (float*)d_out;

  char* w = (char*)d_ws;
  size_t off = 0;
  auto take = [&](size_t bytes) {
    char* p = w + off;
    off += (bytes + 255) & ~(size_t)255;
    return p;
  };
  bf16* xb    = (bf16*)take(4096ull * 1024 * 2);
  bf16* Wqkvt = (bf16*)take(3072ull * 1024 * 2);
  bf16* Wot   = (bf16*)take(1024ull * 1024 * 2);
  bf16* W1t   = (bf16*)take(2048ull * 1024 * 2);
  bf16* W2t   = (bf16*)take(1024ull * 2048 * 2);
  bf16* QKV   = (bf16*)take(4096ull * 3072 * 2);
  bf16* Vt    = (bf16*)take(1024ull * 4096 * 2);
  bf16* AO    = (bf16*)take(4096ull * 1024 * 2);
  u64*  adjbits = (u64*)take(4096ull * 64 * 8);
  float* lpart  = (float*)take(4ull * 4096 * 8 * 4);
  // 32MB region reused over time: AOpart (until attn_norm) -> WoP (after)
  char* big = take(32ull << 20);
  bf16*  AOpart = (bf16*)big;                       // 4 x 8MB bf16
  float* WoP    = (float*)big;                      // 16MB f32
  float* H   = (float*)take(4096ull * 1024 * 4);
  bf16*  FLN = (bf16*)take(4096ull * 1024 * 2);
  bf16*  G   = (bf16*)take(4096ull * 2048 * 2);

  dim3 tb(32, 8);
  // fused: x cvt + adj bits + all weight transposes (12288 blocks total)
  prep_all<<<12288, 256, 0, stream>>>(x, xb, adj, adjbits, Wq, Wk, Wv, Wo, W1, W2,
                                      Wqkvt, Wot, W1t, W2t);
  // QKV = xb @ [Wq|Wk|Wv]   (bf16 out)
  gemm_bt<0, 128><<<dim3(24, 32), 256, 0, stream>>>(xb, Wqkvt, nullptr, nullptr,
                                                    nullptr, QKV, 4096, 3072, 1024);
  // plain V^T per head: Vt[h*128+dh][n]
  tr_bf16t<<<dim3(32, 128), tb, 0, stream>>>(QKV + 2048, Vt, 3072);
  // flash attention, split-K x4
  attn_kernel<<<dim3(32, 8, 4), 256, 0, stream>>>(QKV, Vt, adjbits, adjb, AOpart, lpart);
  attn_norm<<<4096, 256, 0, stream>>>(AOpart, lpart, AO);
  // WoP = AO @ Wo + Wo_b   (f32 out; 128x64 tiles -> 512 blocks, no split-K)
  gemm_bt<1, 64><<<dim3(16, 32), 256, 0, stream>>>(AO, Wot, Wob, nullptr,
                                                   WoP, nullptr, 4096, 1024, 1024);
  // h = LN(x + WoP); FLN = bf16(LN(h))
  ln2_kernel<<<4096, 256, 0, stream>>>(x, WoP, g1, b1, g2, b2, H, FLN);
  // G = gelu(FLN @ W1 + b1)   (bf16 out)
  gemm_bt<2, 128><<<dim3(16, 32), 256, 0, stream>>>(FLN, W1t, fb1, nullptr,
                                                    nullptr, G, 4096, 2048, 1024);
  // out = G @ W2 + b2 + h   (f32 out; 128x64 tiles -> 512 blocks, no split-K)
  gemm_bt<3, 64><<<dim3(16, 32), 256, 0, stream>>>(G, W2t, fb2, H,
                                                   out, nullptr, 4096, 1024, 2048);
}

// Round 8
// 415.286 us; speedup vs baseline: 1.3538x; 1.0166x over previous
//
#include <hip/hip_runtime.h>
#include <hip/hip_bf16.h>
#include <cstdint>
#include <cstddef>

typedef __hip_bfloat16 bf16;
typedef __attribute__((ext_vector_type(8))) short short8;
typedef __attribute__((ext_vector_type(4))) short short4v;
typedef __attribute__((ext_vector_type(4))) float floatx4;
typedef unsigned long long u64;

#define DEVI static __device__ __forceinline__

DEVI void load_lds16(const void* g, void* l) {
  __builtin_amdgcn_global_load_lds((const __attribute__((address_space(1))) unsigned int*)g,
                                   (__attribute__((address_space(3))) unsigned int*)l, 16, 0, 0);
}
DEVI short8 ld8(const bf16* p) { return *(const short8*)p; }
DEVI floatx4 mfma16(short8 a, short8 b, floatx4 c) {
  return __builtin_amdgcn_mfma_f32_16x16x32_bf16(a, b, c, 0, 0, 0);
}
DEVI short bfb(float f) { bf16 h = __float2bfloat16(f); return __builtin_bit_cast(short, h); }
DEVI float fbf(short s) { bf16 h = __builtin_bit_cast(bf16, s); return __bfloat162float(h); }

// ---------------- fused prep: x->bf16 + adj bits + all 6 weight transposes ----------------
// Block budget: 4096 (x/adj) + 4096 (Wq,Wk,Wv,Wo) + 2048 (W1) + 2048 (W2) = 12288.
DEVI void tr_tile(const float* in, bf16* out, int R, int C, int bx, int by) {
  __shared__ float t[32][33];
  int c0 = bx * 32, r0 = by * 32;
  int tx = threadIdx.x & 31, ty = threadIdx.x >> 5;
#pragma unroll
  for (int i = 0; i < 32; i += 8) t[ty + i][tx] = in[(size_t)(r0 + ty + i) * C + c0 + tx];
  __syncthreads();
#pragma unroll
  for (int i = 0; i < 32; i += 8)
    out[(size_t)(c0 + ty + i) * R + r0 + tx] = __float2bfloat16(t[tx][ty + i]);
}

__global__ __launch_bounds__(256)
void prep_all(const float* __restrict__ x, bf16* __restrict__ xb,
              const float* __restrict__ adj, u64* __restrict__ bits,
              const float* Wq, const float* Wk, const float* Wv, const float* Wo,
              const float* W1, const float* W2,
              bf16* Wqkvt, bf16* Wot, bf16* W1t, bf16* W2t) {
  int id = blockIdx.x;
  if (id < 4096) {
    const int row = id, tid = threadIdx.x;
    const int wave = tid >> 6, lane = tid & 63;
    float4 v = ((const float4*)(x + (size_t)row * 1024))[tid];
    bf16* o = xb + (size_t)row * 1024 + tid * 4;
    o[0] = __float2bfloat16(v.x); o[1] = __float2bfloat16(v.y);
    o[2] = __float2bfloat16(v.z); o[3] = __float2bfloat16(v.w);
    const float* arow = adj + (size_t)row * 4096;
#pragma unroll
    for (int it = 0; it < 16; it++) {
      int col = it * 256 + tid;
      u64 m = __ballot(arow[col] != 0.f);
      if (lane == 0) bits[(size_t)row * 64 + it * 4 + wave] = m;
    }
  } else if (id < 8192) {
    int q = id - 4096, w = q >> 10, t = q & 1023;
    const float* in = w == 0 ? Wq : w == 1 ? Wk : w == 2 ? Wv : Wo;
    bf16* out = w == 0 ? Wqkvt : w == 1 ? Wqkvt + 1024ull * 1024
              : w == 2 ? Wqkvt + 2048ull * 1024 : Wot;
    tr_tile(in, out, 1024, 1024, t & 31, t >> 5);
  } else if (id < 10240) {
    int t = id - 8192;
    tr_tile(W1, W1t, 1024, 2048, t & 63, t >> 6);
  } else {
    int t = id - 10240;
    tr_tile(W2, W2t, 2048, 1024, t & 31, t >> 5);
  }
}

// ---------------- plain V^T build: out[dh][n] = V[n][dh] ----------------
__global__ __launch_bounds__(256)
void tr_bf16t(const bf16* __restrict__ in, bf16* __restrict__ out, int inLd) {
  __shared__ bf16 t[32][33];
  int c0 = blockIdx.x * 32, r0 = blockIdx.y * 32;
  int tx = threadIdx.x, ty = threadIdx.y;
#pragma unroll
  for (int i = 0; i < 32; i += 8) t[ty + i][tx] = in[(size_t)(r0 + ty + i) * inLd + c0 + tx];
  __syncthreads();
#pragma unroll
  for (int i = 0; i < 32; i += 8)
    out[(size_t)(c0 + ty + i) * 4096 + r0 + tx] = t[tx][ty + i];
}

// ---------------- bf16 GEMM, C = A[M][K] @ Bt[N][K]^T, tile 128 x BN ----------------
// Pipelined K-loop: 3 LDS buffers, loads 2 tiles in flight, raw s_barrier with
// fine-grained vmcnt (never vmcnt(0) mid-loop).
// MODE 0: bf16 C (QKV) | MODE 2: bf16 gelu(C+bias) (FFN1)
// MODE 1: f32 C + bias (Wo, BN=64) | MODE 3: f32 C + bias + resid (FFN2, BN=64)
template <int MODE, int BN>
__global__ __launch_bounds__(256)
void gemm_bt(const bf16* __restrict__ A, const bf16* __restrict__ Bt,
             const float* __restrict__ bias, const float* __restrict__ resid,
             float* __restrict__ outF, bf16* __restrict__ outB,
             int M, int Nn, int K) {
  constexpr int NI = BN / 32;          // mfma col-tiles per wave
  __shared__ alignas(16) bf16 As[3][128 * 32];
  __shared__ alignas(16) bf16 Bs[3][BN * 32];
  const int tid = threadIdx.x;
  const int wave = tid >> 6, lane = tid & 63;
  const int m0 = blockIdx.y * 128, n0 = blockIdx.x * BN;
  const int wr = (wave >> 1) * 64, wc = (wave & 1) * (BN / 2);
  const int l15 = lane & 15, qq = lane >> 4;
  const int lr = lane >> 2, l4 = lane & 3;
  const int T = K >> 5;

  floatx4 acc[4][NI];
#pragma unroll
  for (int i = 0; i < 4; i++)
#pragma unroll
    for (int j = 0; j < NI; j++) acc[i][j] = (floatx4)0.f;

  const bf16* gA0 = A + (size_t)(m0 + wave * 16 + lr) * K + l4 * 8;
  const bf16* gA1 = gA0 + (size_t)64 * K;
  const bf16* gB0 = Bt + (size_t)(n0 + wave * 16 + lr) * K + l4 * 8;
  const bf16* gB1 = gB0 + (size_t)64 * K;
  const int lo = wave * 16 * 32;

  auto stage = [&](int t, int buf) {
    int kt = t * 32;
    load_lds16(gA0 + kt, &As[buf][lo]);
    load_lds16(gA1 + kt, &As[buf][64 * 32 + lo]);
    load_lds16(gB0 + kt, &Bs[buf][lo]);
    if (BN == 128) load_lds16(gB1 + kt, &Bs[buf][64 * 32 + lo]);
  };
  stage(0, 0);
  stage(1, 1);

  int bc = 0;
  for (int t = 0; t < T; ++t) {
    if (t < T - 1) {
      if constexpr (BN == 128)
        asm volatile("s_waitcnt vmcnt(4) lgkmcnt(0)" ::: "memory");
      else
        asm volatile("s_waitcnt vmcnt(3) lgkmcnt(0)" ::: "memory");
    } else {
      asm volatile("s_waitcnt vmcnt(0) lgkmcnt(0)" ::: "memory");
    }
    __builtin_amdgcn_s_barrier();
    if (t + 2 < T) { int bs = bc == 0 ? 2 : bc - 1; stage(t + 2, bs); }

    short8 af[4], bfr[NI];
#pragma unroll
    for (int mi = 0; mi < 4; mi++) af[mi] = ld8(&As[bc][(wr + mi * 16 + l15) * 32 + qq * 8]);
#pragma unroll
    for (int ni = 0; ni < NI; ni++) bfr[ni] = ld8(&Bs[bc][(wc + ni * 16 + l15) * 32 + qq * 8]);
#pragma unroll
    for (int mi = 0; mi < 4; mi++)
#pragma unroll
      for (int ni = 0; ni < NI; ni++)
        acc[mi][ni] = mfma16(af[mi], bfr[ni], acc[mi][ni]);
    bc = bc == 2 ? 0 : bc + 1;
  }

#pragma unroll
  for (int mi = 0; mi < 4; mi++) {
    int row = m0 + wr + mi * 16 + qq * 4;
#pragma unroll
    for (int ni = 0; ni < NI; ni++) {
      int col = n0 + wc + ni * 16 + l15;
      float bv = (MODE >= 1) ? bias[col] : 0.f;
#pragma unroll
      for (int r = 0; r < 4; r++) {
        float v = acc[mi][ni][r] + bv;
        size_t off = (size_t)(row + r) * Nn + col;
        if (MODE == 0) {
          outB[off] = __float2bfloat16(v);
        } else if (MODE == 2) {
          outB[off] = __float2bfloat16(0.5f * v * (1.f + erff(v * 0.70710678118654752f)));
        } else if (MODE == 1) {
          outF[off] = v;
        } else {
          outF[off] = v + resid[off];
        }
      }
    }
  }
}

// ---------------- flash attention v21: split-K=2, l via MFMA ones-column ----------------
// grid (32 q-tiles, 8 heads, 2 splits) = 512 blocks = exactly 2/CU x 256 CU: ONE
// dispatch round (split-4 was two rounds -> paid block prologue/epilogue twice).
// AOpart traffic halved (16MB vs 32MB each way).
// Softmax denominator l[q] = sum_k P[q,k] computed as PV against a ones B-frag
// (o8 = mfma16(pa, ones)): removes the lrow VALU adds + epilogue shuffle-reduce,
// and uses the same bf16 P as the numerator (consistent rounding).
// Schedule per 32-key window (R7): V reg-prefetch -> 4-chain QK (setprio 1) ->
// softmax -> K=32 PV from registers (setprio 1). K staged permuted for K=32 PV.
__global__ __launch_bounds__(256, 2)
void attn_kernel(const bf16* __restrict__ QKV, const bf16* __restrict__ Vt,
                 const u64* __restrict__ adjbits, const float* __restrict__ adj_bias,
                 bf16* __restrict__ AOpart, float* __restrict__ lpart) {
  __shared__ alignas(16) bf16 Kf[2][16 * 512];  // frag fi=ni*4+kk: permuted K rows x 32 k-dims
  __shared__ alignas(16) bf16 Vf[2][16 * 512];  // frag fi=d*2+k2:  V^T[d*16+l15][kt+k2*32+..]
  const int q0 = blockIdx.x * 128;
  const int h = blockIdx.y;
  const int split = blockIdx.z;
  const int k0 = split * 2048;
  const int tid = threadIdx.x, wave = tid >> 6, lane = tid & 63;
  const int l15 = lane & 15, qq = lane >> 4;
  const float log2e = 1.4426950408889634f;
  const float beta2 = adj_bias[h] * log2e;
  const float scale2 = 0.08838834764831845f * log2e;  // 128^-0.5 * log2(e)

  // Q fragments (B-operand; 32 rows per wave)
  short8 qf[2][4];
#pragma unroll
  for (int mi = 0; mi < 2; mi++)
#pragma unroll
    for (int kk = 0; kk < 4; kk++)
      qf[mi][kk] = ld8(&QKV[(size_t)(q0 + wave * 32 + mi * 16 + l15) * 3072 +
                            h * 128 + kk * 32 + qq * 8]);

  floatx4 o[2][8];
#pragma unroll
  for (int mi = 0; mi < 2; mi++)
#pragma unroll
    for (int d = 0; d < 8; d++) o[mi][d] = (floatx4)0.f;
  floatx4 o8[2] = {(floatx4)0.f, (floatx4)0.f};   // l accumulator (D rows = q)
  short8 ones;
#pragma unroll
  for (int i = 0; i < 8; i++) ones[i] = (short)0x3F80;  // bf16 1.0

  const size_t abase = (size_t)(q0 + wave * 32 + l15) * 64 + split * 32;
  // key permutation within a 32-key window (slot l15 -> key offset), +4 for odd ni
  const int kperm = ((l15 >> 2) * 8) + (l15 & 3);

  auto stage = [&](int t, int buf) {
    const int kt = k0 + t * 64;
#pragma unroll
    for (int i = 0; i < 4; i++) {
      int fi = wave * 4 + i;
      int ni = fi >> 2, kk = fi & 3;
      int krow = kt + (ni >> 1) * 32 + (ni & 1) * 4 + kperm;
      load_lds16(&QKV[(size_t)krow * 3072 + 1024 + h * 128 + kk * 32 + qq * 8],
                 (char*)Kf[buf] + fi * 1024);
      int d = fi >> 1, k2 = fi & 1;
      load_lds16(&Vt[(size_t)(h * 128 + d * 16 + l15) * 4096 + kt + k2 * 32 + qq * 8],
                 (char*)Vf[buf] + fi * 1024);
    }
  };

  // prologue: stage tile 0, prefetch adj words for tile 0
  stage(0, 0);
  u64 a0c = adjbits[abase];
  u64 a1c = adjbits[abase + 1024];

  for (int t = 0; t < 32; t++) {
    // __syncthreads drains this wave's in-flight stage+adj loads and makes
    // buf[t&1] visible; all waves are also done reading buf[(t+1)&1].
    __syncthreads();
    if (t < 31) stage(t + 1, (t + 1) & 1);
    u64 a0n = 0, a1n = 0;
    if (t < 31) { a0n = adjbits[abase + t + 1]; a1n = adjbits[abase + 1024 + t + 1]; }

    const bf16* Kc = Kf[t & 1];
    const bf16* Vc = Vf[t & 1];
    const uint32_t w0lo = (uint32_t)a0c, w0hi = (uint32_t)(a0c >> 32);
    const uint32_t w1lo = (uint32_t)a1c, w1hi = (uint32_t)(a1c >> 32);

    // per 32-key window: V reg-prefetch, then 4-chain QK, softmax, K=32 PV
#pragma unroll
    for (int ni2 = 0; ni2 < 2; ni2++) {
      // (a) V-frag register prefetch: issued first so PV never waits on LDS
      short8 vreg[8];
#pragma unroll
      for (int d = 0; d < 8; d++)
        vreg[d] = ld8((const bf16*)((const char*)Vc + (d * 2 + ni2) * 1024 +
                                    qq * 256 + l15 * 16));
      // (b) both hh steps' QK as 4 independent MFMA chains
      floatx4 s00 = (floatx4)0.f, s10 = (floatx4)0.f;  // hh=0: subtile 0,1
      floatx4 s01 = (floatx4)0.f, s11 = (floatx4)0.f;  // hh=1: subtile 0,1
      __builtin_amdgcn_s_setprio(1);
#pragma unroll
      for (int kk = 0; kk < 4; kk++) {
        short8 kfr0 = ld8(&Kc[((ni2 * 2 + 0) * 4 + kk) * 512 + lane * 8]);
        s00 = mfma16(kfr0, qf[0][kk], s00);
        s10 = mfma16(kfr0, qf[1][kk], s10);
      }
#pragma unroll
      for (int kk = 0; kk < 4; kk++) {
        short8 kfr1 = ld8(&Kc[((ni2 * 2 + 1) * 4 + kk) * 512 + lane * 8]);
        s01 = mfma16(kfr1, qf[0][kk], s01);
        s11 = mfma16(kfr1, qf[1][kk], s11);
      }
      __builtin_amdgcn_s_setprio(0);
      // softmax both hh steps -> short8 P A-frags
      short8 pa0, pa1;
      {
        const int bp = qq * 8;
        // hh = 0
        uint32_t u0 = (ni2 ? w0hi : w0lo);
        uint32_t u1 = (ni2 ? w1hi : w1lo);
        float p0, p1, p2, p3;
        p0 = __builtin_amdgcn_exp2f(fmaf(s00[0], scale2, ((u0 >> (bp + 0)) & 1) ? beta2 : 0.f));
        p1 = __builtin_amdgcn_exp2f(fmaf(s00[1], scale2, ((u0 >> (bp + 1)) & 1) ? beta2 : 0.f));
        p2 = __builtin_amdgcn_exp2f(fmaf(s00[2], scale2, ((u0 >> (bp + 2)) & 1) ? beta2 : 0.f));
        p3 = __builtin_amdgcn_exp2f(fmaf(s00[3], scale2, ((u0 >> (bp + 3)) & 1) ? beta2 : 0.f));
        pa0[0] = bfb(p0); pa0[1] = bfb(p1); pa0[2] = bfb(p2); pa0[3] = bfb(p3);
        p0 = __builtin_amdgcn_exp2f(fmaf(s10[0], scale2, ((u1 >> (bp + 0)) & 1) ? beta2 : 0.f));
        p1 = __builtin_amdgcn_exp2f(fmaf(s10[1], scale2, ((u1 >> (bp + 1)) & 1) ? beta2 : 0.f));
        p2 = __builtin_amdgcn_exp2f(fmaf(s10[2], scale2, ((u1 >> (bp + 2)) & 1) ? beta2 : 0.f));
        p3 = __builtin_amdgcn_exp2f(fmaf(s10[3], scale2, ((u1 >> (bp + 3)) & 1) ? beta2 : 0.f));
        pa1[0] = bfb(p0); pa1[1] = bfb(p1); pa1[2] = bfb(p2); pa1[3] = bfb(p3);
        // hh = 1 (bits shifted by 4)
        u0 >>= 4; u1 >>= 4;
        p0 = __builtin_amdgcn_exp2f(fmaf(s01[0], scale2, ((u0 >> (bp + 0)) & 1) ? beta2 : 0.f));
        p1 = __builtin_amdgcn_exp2f(fmaf(s01[1], scale2, ((u0 >> (bp + 1)) & 1) ? beta2 : 0.f));
        p2 = __builtin_amdgcn_exp2f(fmaf(s01[2], scale2, ((u0 >> (bp + 2)) & 1) ? beta2 : 0.f));
        p3 = __builtin_amdgcn_exp2f(fmaf(s01[3], scale2, ((u0 >> (bp + 3)) & 1) ? beta2 : 0.f));
        pa0[4] = bfb(p0); pa0[5] = bfb(p1); pa0[6] = bfb(p2); pa0[7] = bfb(p3);
        p0 = __builtin_amdgcn_exp2f(fmaf(s11[0], scale2, ((u1 >> (bp + 0)) & 1) ? beta2 : 0.f));
        p1 = __builtin_amdgcn_exp2f(fmaf(s11[1], scale2, ((u1 >> (bp + 1)) & 1) ? beta2 : 0.f));
        p2 = __builtin_amdgcn_exp2f(fmaf(s11[2], scale2, ((u1 >> (bp + 2)) & 1) ? beta2 : 0.f));
        p3 = __builtin_amdgcn_exp2f(fmaf(s11[3], scale2, ((u1 >> (bp + 3)) & 1) ? beta2 : 0.f));
        pa1[4] = bfb(p0); pa1[5] = bfb(p1); pa1[6] = bfb(p2); pa1[7] = bfb(p3);
      }
      // (c) PV, K=32, from registers only; l-column accumulated via ones B-frag
      __builtin_amdgcn_s_setprio(1);
#pragma unroll
      for (int d = 0; d < 8; d++) {
        o[0][d] = mfma16(pa0, vreg[d], o[0][d]);
        o[1][d] = mfma16(pa1, vreg[d], o[1][d]);
      }
      o8[0] = mfma16(pa0, ones, o8[0]);
      o8[1] = mfma16(pa1, ones, o8[1]);
      __builtin_amdgcn_s_setprio(0);
    }
    a0c = a0n; a1c = a1n;
  }

  // epilogue: l comes straight out of o8 (D rows = q = qq*4+r); write bf16 partials
#pragma unroll
  for (int mi = 0; mi < 2; mi++) {
    if (l15 == 0) {
#pragma unroll
      for (int r = 0; r < 4; r++)
        lpart[((size_t)split * 4096 + q0 + wave * 32 + mi * 16 + qq * 4 + r) * 8 + h] =
            o8[mi][r];
    }
#pragma unroll
    for (int r = 0; r < 4; r++) {
      int grow = q0 + wave * 32 + mi * 16 + qq * 4 + r;
      bf16* dst = AOpart + ((size_t)split * 4096 + grow) * 1024 + h * 128;
#pragma unroll
      for (int d = 0; d < 8; d++) dst[d * 16 + l15] = __float2bfloat16(o[mi][d][r]);
    }
  }
}

// ---------------- combine split-K partials (2 splits), normalize -> bf16 AO ----------------
__global__ __launch_bounds__(256)
void attn_norm(const bf16* __restrict__ AOpart, const float* __restrict__ lpart,
               bf16* __restrict__ AO) {
  int row = blockIdx.x, tid = threadIdx.x;
  int h = tid >> 5;
  float ls = 0.f;
#pragma unroll
  for (int s = 0; s < 2; s++) ls += lpart[((size_t)s * 4096 + row) * 8 + h];
  float a0 = 0.f, a1 = 0.f, a2 = 0.f, a3 = 0.f;
#pragma unroll
  for (int s = 0; s < 2; s++) {
    short4v v = *(const short4v*)&AOpart[((size_t)s * 4096 + row) * 1024 + tid * 4];
    a0 += fbf(v.x); a1 += fbf(v.y); a2 += fbf(v.z); a3 += fbf(v.w);
  }
  float inv = 1.f / ls;
  bf16* op = AO + (size_t)row * 1024 + tid * 4;
  op[0] = __float2bfloat16(a0 * inv);
  op[1] = __float2bfloat16(a1 * inv);
  op[2] = __float2bfloat16(a2 * inv);
  op[3] = __float2bfloat16(a3 * inv);
}

// ---------------- fused double-LayerNorm ----------------
DEVI void block_sum2(float& a, float& b, float* red) {
#pragma unroll
  for (int o = 1; o < 64; o <<= 1) { a += __shfl_xor(a, o, 64); b += __shfl_xor(b, o, 64); }
  int wv = threadIdx.x >> 6;
  if ((threadIdx.x & 63) == 0) { red[wv] = a; red[4 + wv] = b; }
  __syncthreads();
  a = red[0] + red[1] + red[2] + red[3];
  b = red[4] + red[5] + red[6] + red[7];
  __syncthreads();
}

__global__ __launch_bounds__(256)
void ln2_kernel(const float* __restrict__ x, const float* __restrict__ ao,
                const float* __restrict__ g1, const float* __restrict__ b1,
                const float* __restrict__ g2, const float* __restrict__ b2,
                float* __restrict__ hout, bf16* __restrict__ fln) {
  __shared__ float red[8];
  const int row = blockIdx.x, tid = threadIdx.x;
  float4 xv = ((const float4*)(x + (size_t)row * 1024))[tid];
  float4 av = ((const float4*)(ao + (size_t)row * 1024))[tid];
  float s0 = xv.x + av.x, s1 = xv.y + av.y, s2 = xv.z + av.z, s3 = xv.w + av.w;
  float sum = s0 + s1 + s2 + s3;
  float ssq = s0 * s0 + s1 * s1 + s2 * s2 + s3 * s3;
  block_sum2(sum, ssq, red);
  float mu = sum * (1.f / 1024.f);
  float rs = rsqrtf(ssq * (1.f / 1024.f) - mu * mu + 1e-5f);
  float4 gv = ((const float4*)g1)[tid], bv = ((const float4*)b1)[tid];
  float h0 = (s0 - mu) * rs * gv.x + bv.x;
  float h1 = (s1 - mu) * rs * gv.y + bv.y;
  float h2 = (s2 - mu) * rs * gv.z + bv.z;
  float h3 = (s3 - mu) * rs * gv.w + bv.w;
  float4 hv; hv.x = h0; hv.y = h1; hv.z = h2; hv.w = h3;
  ((float4*)(hout + (size_t)row * 1024))[tid] = hv;
  float sum2 = h0 + h1 + h2 + h3;
  float ssq2 = h0 * h0 + h1 * h1 + h2 * h2 + h3 * h3;
  block_sum2(sum2, ssq2, red);
  float mu2 = sum2 * (1.f / 1024.f);
  float rs2 = rsqrtf(ssq2 * (1.f / 1024.f) - mu2 * mu2 + 1e-5f);
  float4 g2v = ((const float4*)g2)[tid], b2v = ((const float4*)b2)[tid];
  bf16* op = fln + (size_t)row * 1024 + tid * 4;
  op[0] = __float2bfloat16((h0 - mu2) * rs2 * g2v.x + b2v.x);
  op[1] = __float2bfloat16((h1 - mu2) * rs2 * g2v.y + b2v.y);
  op[2] = __float2bfloat16((h2 - mu2) * rs2 * g2v.z + b2v.z);
  op[3] = __float2bfloat16((h3 - mu2) * rs2 * g2v.w + b2v.w);
}

// ---------------- host launch ----------------
extern "C" void kernel_launch(void* const* d_in, const int* in_sizes, int n_in,
                              void* d_out, int out_size, void* d_ws, size_t ws_size,
                              hipStream_t stream) {
  const float* x    = (const float*)d_in[0];
  const float* adj  = (const float*)d_in[1];
  const float* Wq   = (const float*)d_in[2];
  const float* Wk   = (const float*)d_in[3];
  const float* Wv   = (const float*)d_in[4];
  const float* Wo   = (const float*)d_in[5];
  const float* Wob  = (const float*)d_in[6];
  const float* adjb = (const float*)d_in[7];
  const float* g1   = (const float*)d_in[8];
  const float* b1   = (const float*)d_in[9];
  const float* g2   = (const float*)d_in[10];
  const float* b2   = (const float*)d_in[11];
  const float* W1   = (const float*)d_in[12];
  const float* fb1  = (const float*)d_in[13];
  const float* W2   = (const float*)d_in[14];
  const float* fb2  = (const float*)d_in[15];
  float* out = (float*)d_out;

  char* w = (char*)d_ws;
  size_t off = 0;
  auto take = [&](size_t bytes) {
    char* p = w + off;
    off += (bytes + 255) & ~(size_t)255;
    return p;
  };
  bf16* xb    = (bf16*)take(4096ull * 1024 * 2);
  bf16* Wqkvt = (bf16*)take(3072ull * 1024 * 2);
  bf16* Wot   = (bf16*)take(1024ull * 1024 * 2);
  bf16* W1t   = (bf16*)take(2048ull * 1024 * 2);
  bf16* W2t   = (bf16*)take(1024ull * 2048 * 2);
  bf16* QKV   = (bf16*)take(4096ull * 3072 * 2);
  bf16* Vt    = (bf16*)take(1024ull * 4096 * 2);
  bf16* AO    = (bf16*)take(4096ull * 1024 * 2);
  u64*  adjbits = (u64*)take(4096ull * 64 * 8);
  float* lpart  = (float*)take(4ull * 4096 * 8 * 4);
  // 32MB region reused over time: AOpart (until attn_norm) -> WoP (after)
  char* big = take(32ull << 20);
  bf16*  AOpart = (bf16*)big;                       // 2 x 8MB bf16
  float* WoP    = (float*)big;                      // 16MB f32
  float* H   = (float*)take(4096ull * 1024 * 4);
  bf16*  FLN = (bf16*)take(4096ull * 1024 * 2);
  bf16*  G   = (bf16*)take(4096ull * 2048 * 2);

  dim3 tb(32, 8);
  // fused: x cvt + adj bits + all weight transposes (12288 blocks total)
  prep_all<<<12288, 256, 0, stream>>>(x, xb, adj, adjbits, Wq, Wk, Wv, Wo, W1, W2,
                                      Wqkvt, Wot, W1t, W2t);
  // QKV = xb @ [Wq|Wk|Wv]   (bf16 out)
  gemm_bt<0, 128><<<dim3(24, 32), 256, 0, stream>>>(xb, Wqkvt, nullptr, nullptr,
                                                    nullptr, QKV, 4096, 3072, 1024);
  // plain V^T per head: Vt[h*128+dh][n]
  tr_bf16t<<<dim3(32, 128), tb, 0, stream>>>(QKV + 2048, Vt, 3072);
  // flash attention, split-K x2 (512 blocks = one clean round at 2/CU)
  attn_kernel<<<dim3(32, 8, 2), 256, 0, stream>>>(QKV, Vt, adjbits, adjb, AOpart, lpart);
  attn_norm<<<4096, 256, 0, stream>>>(AOpart, lpart, AO);
  // WoP = AO @ Wo + Wo_b   (f32 out; 128x64 tiles -> 512 blocks, no split-K)
  gemm_bt<1, 64><<<dim3(16, 32), 256, 0, stream>>>(AO, Wot, Wob, nullptr,
                                                   WoP, nullptr, 4096, 1024, 1024);
  // h = LN(x + WoP); FLN = bf16(LN(h))
  ln2_kernel<<<4096, 256, 0, stream>>>(x, WoP, g1, b1, g2, b2, H, FLN);
  // G = gelu(FLN @ W1 + b1)   (bf16 out)
  gemm_bt<2, 128><<<dim3(16, 32), 256, 0, stream>>>(FLN, W1t, fb1, nullptr,
                                                    nullptr, G, 4096, 2048, 1024);
  // out = G @ W2 + b2 + h   (f32 out; 128x64 tiles -> 512 blocks, no split-K)
  gemm_bt<3, 64><<<dim3(16, 32), 256, 0, stream>>>(G, W2t, fb2, H,
                                                   out, nullptr, 4096, 1024, 2048);
}

// Round 9
// 407.594 us; speedup vs baseline: 1.3793x; 1.0189x over previous
//
#include <hip/hip_runtime.h>
#include <hip/hip_bf16.h>
#include <cstdint>
#include <cstddef>

typedef __hip_bfloat16 bf16;
typedef __attribute__((ext_vector_type(8))) short short8;
typedef __attribute__((ext_vector_type(4))) short short4v;
typedef __attribute__((ext_vector_type(4))) float floatx4;
typedef unsigned long long u64;

#define DEVI static __device__ __forceinline__

DEVI void load_lds16(const void* g, void* l) {
  __builtin_amdgcn_global_load_lds((const __attribute__((address_space(1))) unsigned int*)g,
                                   (__attribute__((address_space(3))) unsigned int*)l, 16, 0, 0);
}
DEVI short8 ld8(const bf16* p) { return *(const short8*)p; }
DEVI floatx4 mfma16(short8 a, short8 b, floatx4 c) {
  return __builtin_amdgcn_mfma_f32_16x16x32_bf16(a, b, c, 0, 0, 0);
}
DEVI short bfb(float f) { bf16 h = __float2bfloat16(f); return __builtin_bit_cast(short, h); }
DEVI float fbf(short s) { bf16 h = __builtin_bit_cast(bf16, s); return __bfloat162float(h); }

// softmax 4-pack: p = exp2(s*scale2 + bit?beta2:0) for 4 acc elems, bits u>>(bp+r)
DEVI short4v sm4(floatx4 s, uint32_t u, int bp, float scale2, float beta2) {
  short4v r;
  float p0 = __builtin_amdgcn_exp2f(fmaf(s[0], scale2, ((u >> (bp + 0)) & 1) ? beta2 : 0.f));
  float p1 = __builtin_amdgcn_exp2f(fmaf(s[1], scale2, ((u >> (bp + 1)) & 1) ? beta2 : 0.f));
  float p2 = __builtin_amdgcn_exp2f(fmaf(s[2], scale2, ((u >> (bp + 2)) & 1) ? beta2 : 0.f));
  float p3 = __builtin_amdgcn_exp2f(fmaf(s[3], scale2, ((u >> (bp + 3)) & 1) ? beta2 : 0.f));
  r.x = bfb(p0); r.y = bfb(p1); r.z = bfb(p2); r.w = bfb(p3);
  return r;
}

// ---------------- fused prep: x->bf16 + adj bits + all 6 weight transposes ----------------
// Block budget: 4096 (x/adj) + 4096 (Wq,Wk,Wv,Wo) + 2048 (W1) + 2048 (W2) = 12288.
DEVI void tr_tile(const float* in, bf16* out, int R, int C, int bx, int by) {
  __shared__ float t[32][33];
  int c0 = bx * 32, r0 = by * 32;
  int tx = threadIdx.x & 31, ty = threadIdx.x >> 5;
#pragma unroll
  for (int i = 0; i < 32; i += 8) t[ty + i][tx] = in[(size_t)(r0 + ty + i) * C + c0 + tx];
  __syncthreads();
#pragma unroll
  for (int i = 0; i < 32; i += 8)
    out[(size_t)(c0 + ty + i) * R + r0 + tx] = __float2bfloat16(t[tx][ty + i]);
}

__global__ __launch_bounds__(256)
void prep_all(const float* __restrict__ x, bf16* __restrict__ xb,
              const float* __restrict__ adj, u64* __restrict__ bits,
              const float* Wq, const float* Wk, const float* Wv, const float* Wo,
              const float* W1, const float* W2,
              bf16* Wqkvt, bf16* Wot, bf16* W1t, bf16* W2t) {
  int id = blockIdx.x;
  if (id < 4096) {
    const int row = id, tid = threadIdx.x;
    const int wave = tid >> 6, lane = tid & 63;
    float4 v = ((const float4*)(x + (size_t)row * 1024))[tid];
    bf16* o = xb + (size_t)row * 1024 + tid * 4;
    o[0] = __float2bfloat16(v.x); o[1] = __float2bfloat16(v.y);
    o[2] = __float2bfloat16(v.z); o[3] = __float2bfloat16(v.w);
    const float* arow = adj + (size_t)row * 4096;
#pragma unroll
    for (int it = 0; it < 16; it++) {
      int col = it * 256 + tid;
      u64 m = __ballot(arow[col] != 0.f);
      if (lane == 0) bits[(size_t)row * 64 + it * 4 + wave] = m;
    }
  } else if (id < 8192) {
    int q = id - 4096, w = q >> 10, t = q & 1023;
    const float* in = w == 0 ? Wq : w == 1 ? Wk : w == 2 ? Wv : Wo;
    bf16* out = w == 0 ? Wqkvt : w == 1 ? Wqkvt + 1024ull * 1024
              : w == 2 ? Wqkvt + 2048ull * 1024 : Wot;
    tr_tile(in, out, 1024, 1024, t & 31, t >> 5);
  } else if (id < 10240) {
    int t = id - 8192;
    tr_tile(W1, W1t, 1024, 2048, t & 63, t >> 6);
  } else {
    int t = id - 10240;
    tr_tile(W2, W2t, 2048, 1024, t & 31, t >> 5);
  }
}

// ---------------- plain V^T build: out[dh][n] = V[n][dh] ----------------
__global__ __launch_bounds__(256)
void tr_bf16t(const bf16* __restrict__ in, bf16* __restrict__ out, int inLd) {
  __shared__ bf16 t[32][33];
  int c0 = blockIdx.x * 32, r0 = blockIdx.y * 32;
  int tx = threadIdx.x, ty = threadIdx.y;
#pragma unroll
  for (int i = 0; i < 32; i += 8) t[ty + i][tx] = in[(size_t)(r0 + ty + i) * inLd + c0 + tx];
  __syncthreads();
#pragma unroll
  for (int i = 0; i < 32; i += 8)
    out[(size_t)(c0 + ty + i) * 4096 + r0 + tx] = t[tx][ty + i];
}

// ---------------- bf16 GEMM, C = A[M][K] @ Bt[N][K]^T, tile 128 x BN ----------------
// Pipelined K-loop: 3 LDS buffers, loads 2 tiles in flight, raw s_barrier with
// fine-grained vmcnt (never vmcnt(0) mid-loop).
// MODE 0: bf16 C (QKV) | MODE 2: bf16 gelu(C+bias) (FFN1)
// MODE 1: f32 C + bias (Wo, BN=64) | MODE 3: f32 C + bias + resid (FFN2, BN=64)
template <int MODE, int BN>
__global__ __launch_bounds__(256)
void gemm_bt(const bf16* __restrict__ A, const bf16* __restrict__ Bt,
             const float* __restrict__ bias, const float* __restrict__ resid,
             float* __restrict__ outF, bf16* __restrict__ outB,
             int M, int Nn, int K) {
  constexpr int NI = BN / 32;          // mfma col-tiles per wave
  __shared__ alignas(16) bf16 As[3][128 * 32];
  __shared__ alignas(16) bf16 Bs[3][BN * 32];
  const int tid = threadIdx.x;
  const int wave = tid >> 6, lane = tid & 63;
  const int m0 = blockIdx.y * 128, n0 = blockIdx.x * BN;
  const int wr = (wave >> 1) * 64, wc = (wave & 1) * (BN / 2);
  const int l15 = lane & 15, qq = lane >> 4;
  const int lr = lane >> 2, l4 = lane & 3;
  const int T = K >> 5;

  floatx4 acc[4][NI];
#pragma unroll
  for (int i = 0; i < 4; i++)
#pragma unroll
    for (int j = 0; j < NI; j++) acc[i][j] = (floatx4)0.f;

  const bf16* gA0 = A + (size_t)(m0 + wave * 16 + lr) * K + l4 * 8;
  const bf16* gA1 = gA0 + (size_t)64 * K;
  const bf16* gB0 = Bt + (size_t)(n0 + wave * 16 + lr) * K + l4 * 8;
  const bf16* gB1 = gB0 + (size_t)64 * K;
  const int lo = wave * 16 * 32;

  auto stage = [&](int t, int buf) {
    int kt = t * 32;
    load_lds16(gA0 + kt, &As[buf][lo]);
    load_lds16(gA1 + kt, &As[buf][64 * 32 + lo]);
    load_lds16(gB0 + kt, &Bs[buf][lo]);
    if (BN == 128) load_lds16(gB1 + kt, &Bs[buf][64 * 32 + lo]);
  };
  stage(0, 0);
  stage(1, 1);

  int bc = 0;
  for (int t = 0; t < T; ++t) {
    if (t < T - 1) {
      if constexpr (BN == 128)
        asm volatile("s_waitcnt vmcnt(4) lgkmcnt(0)" ::: "memory");
      else
        asm volatile("s_waitcnt vmcnt(3) lgkmcnt(0)" ::: "memory");
    } else {
      asm volatile("s_waitcnt vmcnt(0) lgkmcnt(0)" ::: "memory");
    }
    __builtin_amdgcn_s_barrier();
    if (t + 2 < T) { int bs = bc == 0 ? 2 : bc - 1; stage(t + 2, bs); }

    short8 af[4], bfr[NI];
#pragma unroll
    for (int mi = 0; mi < 4; mi++) af[mi] = ld8(&As[bc][(wr + mi * 16 + l15) * 32 + qq * 8]);
#pragma unroll
    for (int ni = 0; ni < NI; ni++) bfr[ni] = ld8(&Bs[bc][(wc + ni * 16 + l15) * 32 + qq * 8]);
#pragma unroll
    for (int mi = 0; mi < 4; mi++)
#pragma unroll
      for (int ni = 0; ni < NI; ni++)
        acc[mi][ni] = mfma16(af[mi], bfr[ni], acc[mi][ni]);
    bc = bc == 2 ? 0 : bc + 1;
  }

#pragma unroll
  for (int mi = 0; mi < 4; mi++) {
    int row = m0 + wr + mi * 16 + qq * 4;
#pragma unroll
    for (int ni = 0; ni < NI; ni++) {
      int col = n0 + wc + ni * 16 + l15;
      float bv = (MODE >= 1) ? bias[col] : 0.f;
#pragma unroll
      for (int r = 0; r < 4; r++) {
        float v = acc[mi][ni][r] + bv;
        size_t off = (size_t)(row + r) * Nn + col;
        if (MODE == 0) {
          outB[off] = __float2bfloat16(v);
        } else if (MODE == 2) {
          outB[off] = __float2bfloat16(0.5f * v * (1.f + erff(v * 0.70710678118654752f)));
        } else if (MODE == 1) {
          outF[off] = v;
        } else {
          outF[off] = v + resid[off];
        }
      }
    }
  }
}

// ---------------- flash attention v22: window-pipelined schedule ----------------
// grid (32 q-tiles, 8 heads, 2 splits) = 512 blocks = 2/CU, one round; 256 thr.
// R8 counters: VALU 35.6us + MFMA 30us + LDS(est) 41us ~= 106.5us wall -> the three
// pipes run SERIALLY per wave. This version software-pipelines the two 32-key windows
// of each iter: loads(w0) -> QK(w0) -> loads(w1) -> QK(w1) -> SM(w0) -> PV(w0) ->
// SM(w1) -> PV(w1). Window-1 LDS reads + QK MFMAs issue before window-0's softmax
// VALU chain executes -> cross-pipe overlap within a wave. Peak liveness ~164 VGPR
// + 72 acc = 236 <= 256 budget at 2 waves/SIMD (unchanged occupancy).
// l via MFMA ones-column; K staged permuted for K=32 PV (as R8).
__global__ __launch_bounds__(256, 2)
void attn_kernel(const bf16* __restrict__ QKV, const bf16* __restrict__ Vt,
                 const u64* __restrict__ adjbits, const float* __restrict__ adj_bias,
                 bf16* __restrict__ AOpart, float* __restrict__ lpart) {
  __shared__ alignas(16) bf16 Kf[2][16 * 512];  // frag fi=ni*4+kk: permuted K rows x 32 k-dims
  __shared__ alignas(16) bf16 Vf[2][16 * 512];  // frag fi=d*2+k2:  V^T[d*16+l15][kt+k2*32+..]
  const int q0 = blockIdx.x * 128;
  const int h = blockIdx.y;
  const int split = blockIdx.z;
  const int k0 = split * 2048;
  const int tid = threadIdx.x, wave = tid >> 6, lane = tid & 63;
  const int l15 = lane & 15, qq = lane >> 4;
  const float log2e = 1.4426950408889634f;
  const float beta2 = adj_bias[h] * log2e;
  const float scale2 = 0.08838834764831845f * log2e;  // 128^-0.5 * log2(e)

  // Q fragments (B-operand; 32 rows per wave)
  short8 qf[2][4];
#pragma unroll
  for (int mi = 0; mi < 2; mi++)
#pragma unroll
    for (int kk = 0; kk < 4; kk++)
      qf[mi][kk] = ld8(&QKV[(size_t)(q0 + wave * 32 + mi * 16 + l15) * 3072 +
                            h * 128 + kk * 32 + qq * 8]);

  floatx4 o[2][8];
#pragma unroll
  for (int mi = 0; mi < 2; mi++)
#pragma unroll
    for (int d = 0; d < 8; d++) o[mi][d] = (floatx4)0.f;
  floatx4 o8[2] = {(floatx4)0.f, (floatx4)0.f};   // l accumulator (D rows = q)
  short8 ones;
#pragma unroll
  for (int i = 0; i < 8; i++) ones[i] = (short)0x3F80;  // bf16 1.0

  const size_t abase = (size_t)(q0 + wave * 32 + l15) * 64 + split * 32;
  // key permutation within a 32-key window (slot l15 -> key offset), +4 for odd ni
  const int kperm = ((l15 >> 2) * 8) + (l15 & 3);

  auto stage = [&](int t, int buf) {
    const int kt = k0 + t * 64;
#pragma unroll
    for (int i = 0; i < 4; i++) {
      int fi = wave * 4 + i;
      int ni = fi >> 2, kk = fi & 3;
      int krow = kt + (ni >> 1) * 32 + (ni & 1) * 4 + kperm;
      load_lds16(&QKV[(size_t)krow * 3072 + 1024 + h * 128 + kk * 32 + qq * 8],
                 (char*)Kf[buf] + fi * 1024);
      int d = fi >> 1, k2 = fi & 1;
      load_lds16(&Vt[(size_t)(h * 128 + d * 16 + l15) * 4096 + kt + k2 * 32 + qq * 8],
                 (char*)Vf[buf] + fi * 1024);
    }
  };

  // prologue: stage tile 0, prefetch adj words for tile 0
  stage(0, 0);
  u64 a0c = adjbits[abase];
  u64 a1c = adjbits[abase + 1024];

  const int bp = qq * 8;

  for (int t = 0; t < 32; t++) {
    // __syncthreads drains this wave's in-flight stage+adj loads and makes
    // buf[t&1] visible; all waves are also done reading buf[(t+1)&1].
    __syncthreads();
    if (t < 31) stage(t + 1, (t + 1) & 1);
    u64 a0n = 0, a1n = 0;
    if (t < 31) { a0n = adjbits[abase + t + 1]; a1n = adjbits[abase + 1024 + t + 1]; }

    const bf16* Kc = Kf[t & 1];
    const char* Vcb = (const char*)Vf[t & 1];
    const uint32_t w0lo = (uint32_t)a0c, w0hi = (uint32_t)(a0c >> 32);
    const uint32_t w1lo = (uint32_t)a1c, w1hi = (uint32_t)(a1c >> 32);

    // ---- window 0 operand loads ----
    short8 k0r[8], v0r[8];
#pragma unroll
    for (int kk = 0; kk < 4; kk++) {
      k0r[kk]     = ld8(&Kc[(0 * 4 + kk) * 512 + lane * 8]);   // ni2=0, hh=0
      k0r[4 + kk] = ld8(&Kc[(1 * 4 + kk) * 512 + lane * 8]);   // ni2=0, hh=1
    }
#pragma unroll
    for (int d = 0; d < 8; d++)
      v0r[d] = ld8((const bf16*)(Vcb + (d * 2 + 0) * 1024 + qq * 256 + l15 * 16));

    // ---- QK window 0 (4 independent chains) ----
    floatx4 s00 = (floatx4)0.f, s10 = (floatx4)0.f;
    floatx4 s01 = (floatx4)0.f, s11 = (floatx4)0.f;
    __builtin_amdgcn_s_setprio(1);
#pragma unroll
    for (int kk = 0; kk < 4; kk++) {
      s00 = mfma16(k0r[kk], qf[0][kk], s00);
      s10 = mfma16(k0r[kk], qf[1][kk], s10);
    }
#pragma unroll
    for (int kk = 0; kk < 4; kk++) {
      s01 = mfma16(k0r[4 + kk], qf[0][kk], s01);
      s11 = mfma16(k0r[4 + kk], qf[1][kk], s11);
    }
    __builtin_amdgcn_s_setprio(0);

    // ---- window 1 operand loads (overlap SM0/PV0 VALU below) ----
    short8 k1r[8], v1r[8];
#pragma unroll
    for (int kk = 0; kk < 4; kk++) {
      k1r[kk]     = ld8(&Kc[(2 * 4 + kk) * 512 + lane * 8]);   // ni2=1, hh=0
      k1r[4 + kk] = ld8(&Kc[(3 * 4 + kk) * 512 + lane * 8]);   // ni2=1, hh=1
    }
#pragma unroll
    for (int d = 0; d < 8; d++)
      v1r[d] = ld8((const bf16*)(Vcb + (d * 2 + 1) * 1024 + qq * 256 + l15 * 16));

    // ---- QK window 1 ----
    floatx4 u00 = (floatx4)0.f, u10 = (floatx4)0.f;
    floatx4 u01 = (floatx4)0.f, u11 = (floatx4)0.f;
    __builtin_amdgcn_s_setprio(1);
#pragma unroll
    for (int kk = 0; kk < 4; kk++) {
      u00 = mfma16(k1r[kk], qf[0][kk], u00);
      u10 = mfma16(k1r[kk], qf[1][kk], u10);
    }
#pragma unroll
    for (int kk = 0; kk < 4; kk++) {
      u01 = mfma16(k1r[4 + kk], qf[0][kk], u01);
      u11 = mfma16(k1r[4 + kk], qf[1][kk], u11);
    }
    __builtin_amdgcn_s_setprio(0);

    // ---- SM window 0 ----
    short8 pa0, pa1;
    {
      short4v a = sm4(s00, w0lo, bp, scale2, beta2);
      short4v b = sm4(s01, w0lo >> 4, bp, scale2, beta2);
      pa0[0] = a.x; pa0[1] = a.y; pa0[2] = a.z; pa0[3] = a.w;
      pa0[4] = b.x; pa0[5] = b.y; pa0[6] = b.z; pa0[7] = b.w;
      a = sm4(s10, w1lo, bp, scale2, beta2);
      b = sm4(s11, w1lo >> 4, bp, scale2, beta2);
      pa1[0] = a.x; pa1[1] = a.y; pa1[2] = a.z; pa1[3] = a.w;
      pa1[4] = b.x; pa1[5] = b.y; pa1[6] = b.z; pa1[7] = b.w;
    }
    // ---- PV window 0 ----
    __builtin_amdgcn_s_setprio(1);
#pragma unroll
    for (int d = 0; d < 8; d++) {
      o[0][d] = mfma16(pa0, v0r[d], o[0][d]);
      o[1][d] = mfma16(pa1, v0r[d], o[1][d]);
    }
    o8[0] = mfma16(pa0, ones, o8[0]);
    o8[1] = mfma16(pa1, ones, o8[1]);
    __builtin_amdgcn_s_setprio(0);

    // ---- SM window 1 ----
    short8 pb0, pb1;
    {
      short4v a = sm4(u00, w0hi, bp, scale2, beta2);
      short4v b = sm4(u01, w0hi >> 4, bp, scale2, beta2);
      pb0[0] = a.x; pb0[1] = a.y; pb0[2] = a.z; pb0[3] = a.w;
      pb0[4] = b.x; pb0[5] = b.y; pb0[6] = b.z; pb0[7] = b.w;
      a = sm4(u10, w1hi, bp, scale2, beta2);
      b = sm4(u11, w1hi >> 4, bp, scale2, beta2);
      pb1[0] = a.x; pb1[1] = a.y; pb1[2] = a.z; pb1[3] = a.w;
      pb1[4] = b.x; pb1[5] = b.y; pb1[6] = b.z; pb1[7] = b.w;
    }
    // ---- PV window 1 ----
    __builtin_amdgcn_s_setprio(1);
#pragma unroll
    for (int d = 0; d < 8; d++) {
      o[0][d] = mfma16(pb0, v1r[d], o[0][d]);
      o[1][d] = mfma16(pb1, v1r[d], o[1][d]);
    }
    o8[0] = mfma16(pb0, ones, o8[0]);
    o8[1] = mfma16(pb1, ones, o8[1]);
    __builtin_amdgcn_s_setprio(0);

    a0c = a0n; a1c = a1n;
  }

  // epilogue: l comes straight out of o8 (D rows = q = qq*4+r); write bf16 partials
#pragma unroll
  for (int mi = 0; mi < 2; mi++) {
    if (l15 == 0) {
#pragma unroll
      for (int r = 0; r < 4; r++)
        lpart[((size_t)split * 4096 + q0 + wave * 32 + mi * 16 + qq * 4 + r) * 8 + h] =
            o8[mi][r];
    }
#pragma unroll
    for (int r = 0; r < 4; r++) {
      int grow = q0 + wave * 32 + mi * 16 + qq * 4 + r;
      bf16* dst = AOpart + ((size_t)split * 4096 + grow) * 1024 + h * 128;
#pragma unroll
      for (int d = 0; d < 8; d++) dst[d * 16 + l15] = __float2bfloat16(o[mi][d][r]);
    }
  }
}

// ---------------- combine split-K partials (2 splits), normalize -> bf16 AO ----------------
__global__ __launch_bounds__(256)
void attn_norm(const bf16* __restrict__ AOpart, const float* __restrict__ lpart,
               bf16* __restrict__ AO) {
  int row = blockIdx.x, tid = threadIdx.x;
  int h = tid >> 5;
  float ls = 0.f;
#pragma unroll
  for (int s = 0; s < 2; s++) ls += lpart[((size_t)s * 4096 + row) * 8 + h];
  float a0 = 0.f, a1 = 0.f, a2 = 0.f, a3 = 0.f;
#pragma unroll
  for (int s = 0; s < 2; s++) {
    short4v v = *(const short4v*)&AOpart[((size_t)s * 4096 + row) * 1024 + tid * 4];
    a0 += fbf(v.x); a1 += fbf(v.y); a2 += fbf(v.z); a3 += fbf(v.w);
  }
  float inv = 1.f / ls;
  bf16* op = AO + (size_t)row * 1024 + tid * 4;
  op[0] = __float2bfloat16(a0 * inv);
  op[1] = __float2bfloat16(a1 * inv);
  op[2] = __float2bfloat16(a2 * inv);
  op[3] = __float2bfloat16(a3 * inv);
}

// ---------------- fused double-LayerNorm ----------------
DEVI void block_sum2(float& a, float& b, float* red) {
#pragma unroll
  for (int o = 1; o < 64; o <<= 1) { a += __shfl_xor(a, o, 64); b += __shfl_xor(b, o, 64); }
  int wv = threadIdx.x >> 6;
  if ((threadIdx.x & 63) == 0) { red[wv] = a; red[4 + wv] = b; }
  __syncthreads();
  a = red[0] + red[1] + red[2] + red[3];
  b = red[4] + red[5] + red[6] + red[7];
  __syncthreads();
}

__global__ __launch_bounds__(256)
void ln2_kernel(const float* __restrict__ x, const float* __restrict__ ao,
                const float* __restrict__ g1, const float* __restrict__ b1,
                const float* __restrict__ g2, const float* __restrict__ b2,
                float* __restrict__ hout, bf16* __restrict__ fln) {
  __shared__ float red[8];
  const int row = blockIdx.x, tid = threadIdx.x;
  float4 xv = ((const float4*)(x + (size_t)row * 1024))[tid];
  float4 av = ((const float4*)(ao + (size_t)row * 1024))[tid];
  float s0 = xv.x + av.x, s1 = xv.y + av.y, s2 = xv.z + av.z, s3 = xv.w + av.w;
  float sum = s0 + s1 + s2 + s3;
  float ssq = s0 * s0 + s1 * s1 + s2 * s2 + s3 * s3;
  block_sum2(sum, ssq, red);
  float mu = sum * (1.f / 1024.f);
  float rs = rsqrtf(ssq * (1.f / 1024.f) - mu * mu + 1e-5f);
  float4 gv = ((const float4*)g1)[tid], bv = ((const float4*)b1)[tid];
  float h0 = (s0 - mu) * rs * gv.x + bv.x;
  float h1 = (s1 - mu) * rs * gv.y + bv.y;
  float h2 = (s2 - mu) * rs * gv.z + bv.z;
  float h3 = (s3 - mu) * rs * gv.w + bv.w;
  float4 hv; hv.x = h0; hv.y = h1; hv.z = h2; hv.w = h3;
  ((float4*)(hout + (size_t)row * 1024))[tid] = hv;
  float sum2 = h0 + h1 + h2 + h3;
  float ssq2 = h0 * h0 + h1 * h1 + h2 * h2 + h3 * h3;
  block_sum2(sum2, ssq2, red);
  float mu2 = sum2 * (1.f / 1024.f);
  float rs2 = rsqrtf(ssq2 * (1.f / 1024.f) - mu2 * mu2 + 1e-5f);
  float4 g2v = ((const float4*)g2)[tid], b2v = ((const float4*)b2)[tid];
  bf16* op = fln + (size_t)row * 1024 + tid * 4;
  op[0] = __float2bfloat16((h0 - mu2) * rs2 * g2v.x + b2v.x);
  op[1] = __float2bfloat16((h1 - mu2) * rs2 * g2v.y + b2v.y);
  op[2] = __float2bfloat16((h2 - mu2) * rs2 * g2v.z + b2v.z);
  op[3] = __float2bfloat16((h3 - mu2) * rs2 * g2v.w + b2v.w);
}

// ---------------- host launch ----------------
extern "C" void kernel_launch(void* const* d_in, const int* in_sizes, int n_in,
                              void* d_out, int out_size, void* d_ws, size_t ws_size,
                              hipStream_t stream) {
  const float* x    = (const float*)d_in[0];
  const float* adj  = (const float*)d_in[1];
  const float* Wq   = (const float*)d_in[2];
  const float* Wk   = (const float*)d_in[3];
  const float* Wv   = (const float*)d_in[4];
  const float* Wo   = (const float*)d_in[5];
  const float* Wob  = (const float*)d_in[6];
  const float* adjb = (const float*)d_in[7];
  const float* g1   = (const float*)d_in[8];
  const float* b1   = (const float*)d_in[9];
  const float* g2   = (const float*)d_in[10];
  const float* b2   = (const float*)d_in[11];
  const float* W1   = (const float*)d_in[12];
  const float* fb1  = (const float*)d_in[13];
  const float* W2   = (const float*)d_in[14];
  const float* fb2  = (const float*)d_in[15];
  float* out = (float*)d_out;

  char* w = (char*)d_ws;
  size_t off = 0;
  auto take = [&](size_t bytes) {
    char* p = w + off;
    off += (bytes + 255) & ~(size_t)255;
    return p;
  };
  bf16* xb    = (bf16*)take(4096ull * 1024 * 2);
  bf16* Wqkvt = (bf16*)take(3072ull * 1024 * 2);
  bf16* Wot   = (bf16*)take(1024ull * 1024 * 2);
  bf16* W1t   = (bf16*)take(2048ull * 1024 * 2);
  bf16* W2t   = (bf16*)take(1024ull * 2048 * 2);
  bf16* QKV   = (bf16*)take(4096ull * 3072 * 2);
  bf16* Vt    = (bf16*)take(1024ull * 4096 * 2);
  bf16* AO    = (bf16*)take(4096ull * 1024 * 2);
  u64*  adjbits = (u64*)take(4096ull * 64 * 8);
  float* lpart  = (float*)take(4ull * 4096 * 8 * 4);
  // 32MB region reused over time: AOpart (until attn_norm) -> WoP (after)
  char* big = take(32ull << 20);
  bf16*  AOpart = (bf16*)big;                       // 2 x 8MB bf16
  float* WoP    = (float*)big;                      // 16MB f32
  float* H   = (float*)take(4096ull * 1024 * 4);
  bf16*  FLN = (bf16*)take(4096ull * 1024 * 2);
  bf16*  G   = (bf16*)take(4096ull * 2048 * 2);

  dim3 tb(32, 8);
  // fused: x cvt + adj bits + all weight transposes (12288 blocks total)
  prep_all<<<12288, 256, 0, stream>>>(x, xb, adj, adjbits, Wq, Wk, Wv, Wo, W1, W2,
                                      Wqkvt, Wot, W1t, W2t);
  // QKV = xb @ [Wq|Wk|Wv]   (bf16 out)
  gemm_bt<0, 128><<<dim3(24, 32), 256, 0, stream>>>(xb, Wqkvt, nullptr, nullptr,
                                                    nullptr, QKV, 4096, 3072, 1024);
  // plain V^T per head: Vt[h*128+dh][n]
  tr_bf16t<<<dim3(32, 128), tb, 0, stream>>>(QKV + 2048, Vt, 3072);
  // flash attention, split-K x2 (512 blocks = one clean round at 2/CU)
  attn_kernel<<<dim3(32, 8, 2), 256, 0, stream>>>(QKV, Vt, adjbits, adjb, AOpart, lpart);
  attn_norm<<<4096, 256, 0, stream>>>(AOpart, lpart, AO);
  // WoP = AO @ Wo + Wo_b   (f32 out; 128x64 tiles -> 512 blocks, no split-K)
  gemm_bt<1, 64><<<dim3(16, 32), 256, 0, stream>>>(AO, Wot, Wob, nullptr,
                                                   WoP, nullptr, 4096, 1024, 1024);
  // h = LN(x + WoP); FLN = bf16(LN(h))
  ln2_kernel<<<4096, 256, 0, stream>>>(x, WoP, g1, b1, g2, b2, H, FLN);
  // G = gelu(FLN @ W1 + b1)   (bf16 out)
  gemm_bt<2, 128><<<dim3(16, 32), 256, 0, stream>>>(FLN, W1t, fb1, nullptr,
                                                    nullptr, G, 4096, 2048, 1024);
  // out = G @ W2 + b2 + h   (f32 out; 128x64 tiles -> 512 blocks, no split-K)
  gemm_bt<3, 64><<<dim3(16, 32), 256, 0, stream>>>(G, W2t, fb2, H,
                                                   out, nullptr, 4096, 1024, 2048);
}

// Round 10
// 405.102 us; speedup vs baseline: 1.3878x; 1.0062x over previous
//
#include <hip/hip_runtime.h>
#include <hip/hip_bf16.h>
#include <cstdint>
#include <cstddef>

typedef __hip_bfloat16 bf16;
typedef __attribute__((ext_vector_type(8))) short short8;
typedef __attribute__((ext_vector_type(4))) short short4v;
typedef __attribute__((ext_vector_type(4))) float floatx4;
typedef unsigned long long u64;

#define DEVI static __device__ __forceinline__

DEVI void load_lds16(const void* g, void* l) {
  __builtin_amdgcn_global_load_lds((const __attribute__((address_space(1))) unsigned int*)g,
                                   (__attribute__((address_space(3))) unsigned int*)l, 16, 0, 0);
}
DEVI short8 ld8(const bf16* p) { return *(const short8*)p; }
DEVI floatx4 mfma16(short8 a, short8 b, floatx4 c) {
  return __builtin_amdgcn_mfma_f32_16x16x32_bf16(a, b, c, 0, 0, 0);
}
DEVI short bfb(float f) { bf16 h = __float2bfloat16(f); return __builtin_bit_cast(short, h); }
DEVI float fbf(short s) { bf16 h = __builtin_bit_cast(bf16, s); return __bfloat162float(h); }

// softmax 4-pack: p = exp2(s*scale2 + bit?beta2:0) for 4 acc elems, bits u>>(bp+r)
DEVI short4v sm4(floatx4 s, uint32_t u, int bp, float scale2, float beta2) {
  short4v r;
  float p0 = __builtin_amdgcn_exp2f(fmaf(s[0], scale2, ((u >> (bp + 0)) & 1) ? beta2 : 0.f));
  float p1 = __builtin_amdgcn_exp2f(fmaf(s[1], scale2, ((u >> (bp + 1)) & 1) ? beta2 : 0.f));
  float p2 = __builtin_amdgcn_exp2f(fmaf(s[2], scale2, ((u >> (bp + 2)) & 1) ? beta2 : 0.f));
  float p3 = __builtin_amdgcn_exp2f(fmaf(s[3], scale2, ((u >> (bp + 3)) & 1) ? beta2 : 0.f));
  r.x = bfb(p0); r.y = bfb(p1); r.z = bfb(p2); r.w = bfb(p3);
  return r;
}

// ---------------- fused prep: x->bf16 + adj bits + all 6 weight transposes ----------------
// Block budget: 4096 (x/adj) + 4096 (Wq,Wk,Wv,Wo) + 2048 (W1) + 2048 (W2) = 12288.
DEVI void tr_tile(const float* in, bf16* out, int R, int C, int bx, int by) {
  __shared__ float t[32][33];
  int c0 = bx * 32, r0 = by * 32;
  int tx = threadIdx.x & 31, ty = threadIdx.x >> 5;
#pragma unroll
  for (int i = 0; i < 32; i += 8) t[ty + i][tx] = in[(size_t)(r0 + ty + i) * C + c0 + tx];
  __syncthreads();
#pragma unroll
  for (int i = 0; i < 32; i += 8)
    out[(size_t)(c0 + ty + i) * R + r0 + tx] = __float2bfloat16(t[tx][ty + i]);
}

__global__ __launch_bounds__(256)
void prep_all(const float* __restrict__ x, bf16* __restrict__ xb,
              const float* __restrict__ adj, u64* __restrict__ bits,
              const float* Wq, const float* Wk, const float* Wv, const float* Wo,
              const float* W1, const float* W2,
              bf16* Wqkvt, bf16* Wot, bf16* W1t, bf16* W2t) {
  int id = blockIdx.x;
  if (id < 4096) {
    const int row = id, tid = threadIdx.x;
    const int wave = tid >> 6, lane = tid & 63;
    float4 v = ((const float4*)(x + (size_t)row * 1024))[tid];
    bf16* o = xb + (size_t)row * 1024 + tid * 4;
    o[0] = __float2bfloat16(v.x); o[1] = __float2bfloat16(v.y);
    o[2] = __float2bfloat16(v.z); o[3] = __float2bfloat16(v.w);
    const float* arow = adj + (size_t)row * 4096;
#pragma unroll
    for (int it = 0; it < 16; it++) {
      int col = it * 256 + tid;
      u64 m = __ballot(arow[col] != 0.f);
      if (lane == 0) bits[(size_t)row * 64 + it * 4 + wave] = m;
    }
  } else if (id < 8192) {
    int q = id - 4096, w = q >> 10, t = q & 1023;
    const float* in = w == 0 ? Wq : w == 1 ? Wk : w == 2 ? Wv : Wo;
    bf16* out = w == 0 ? Wqkvt : w == 1 ? Wqkvt + 1024ull * 1024
              : w == 2 ? Wqkvt + 2048ull * 1024 : Wot;
    tr_tile(in, out, 1024, 1024, t & 31, t >> 5);
  } else if (id < 10240) {
    int t = id - 8192;
    tr_tile(W1, W1t, 1024, 2048, t & 63, t >> 6);
  } else {
    int t = id - 10240;
    tr_tile(W2, W2t, 2048, 1024, t & 31, t >> 5);
  }
}

// ---------------- plain V^T build: out[dh][n] = V[n][dh] ----------------
__global__ __launch_bounds__(256)
void tr_bf16t(const bf16* __restrict__ in, bf16* __restrict__ out, int inLd) {
  __shared__ bf16 t[32][33];
  int c0 = blockIdx.x * 32, r0 = blockIdx.y * 32;
  int tx = threadIdx.x, ty = threadIdx.y;
#pragma unroll
  for (int i = 0; i < 32; i += 8) t[ty + i][tx] = in[(size_t)(r0 + ty + i) * inLd + c0 + tx];
  __syncthreads();
#pragma unroll
  for (int i = 0; i < 32; i += 8)
    out[(size_t)(c0 + ty + i) * 4096 + r0 + tx] = t[tx][ty + i];
}

// ---------------- bf16 GEMM, C = A[M][K] @ Bt[N][K]^T, tile 128 x BN ----------------
// Pipelined K-loop: 3 LDS buffers, loads 2 tiles in flight, raw s_barrier with
// fine-grained vmcnt (never vmcnt(0) mid-loop). XCD-chunked block swizzle (T1):
// contiguous output tiles per XCD for L2 locality (all grids %8 == 0).
// MODE 0: bf16 C (QKV) | MODE 2: bf16 gelu(C+bias) (FFN1)
// MODE 1: f32 C + bias (Wo, BN=64) | MODE 3: f32 C + bias + resid (FFN2, BN=64)
template <int MODE, int BN>
__global__ __launch_bounds__(256)
void gemm_bt(const bf16* __restrict__ A, const bf16* __restrict__ Bt,
             const float* __restrict__ bias, const float* __restrict__ resid,
             float* __restrict__ outF, bf16* __restrict__ outB,
             int M, int Nn, int K) {
  constexpr int NI = BN / 32;          // mfma col-tiles per wave
  __shared__ alignas(16) bf16 As[3][128 * 32];
  __shared__ alignas(16) bf16 Bs[3][BN * 32];
  const int tid = threadIdx.x;
  const int wave = tid >> 6, lane = tid & 63;
  // XCD-chunked swizzle: dispatched id L%8 = XCD (heuristic); XCD k gets a
  // CONTIGUOUS chunk of logical tiles -> neighbor tiles share A/B panels in L2.
  const int gx = gridDim.x, nwg = gx * gridDim.y;
  const int lin = blockIdx.x + gx * blockIdx.y;
  const int swz = (lin & 7) * (nwg >> 3) + (lin >> 3);
  const int m0 = (swz / gx) * 128, n0 = (swz % gx) * BN;
  const int wr = (wave >> 1) * 64, wc = (wave & 1) * (BN / 2);
  const int l15 = lane & 15, qq = lane >> 4;
  const int lr = lane >> 2, l4 = lane & 3;
  const int T = K >> 5;

  floatx4 acc[4][NI];
#pragma unroll
  for (int i = 0; i < 4; i++)
#pragma unroll
    for (int j = 0; j < NI; j++) acc[i][j] = (floatx4)0.f;

  const bf16* gA0 = A + (size_t)(m0 + wave * 16 + lr) * K + l4 * 8;
  const bf16* gA1 = gA0 + (size_t)64 * K;
  const bf16* gB0 = Bt + (size_t)(n0 + wave * 16 + lr) * K + l4 * 8;
  const bf16* gB1 = gB0 + (size_t)64 * K;
  const int lo = wave * 16 * 32;

  auto stage = [&](int t, int buf) {
    int kt = t * 32;
    load_lds16(gA0 + kt, &As[buf][lo]);
    load_lds16(gA1 + kt, &As[buf][64 * 32 + lo]);
    load_lds16(gB0 + kt, &Bs[buf][lo]);
    if (BN == 128) load_lds16(gB1 + kt, &Bs[buf][64 * 32 + lo]);
  };
  stage(0, 0);
  stage(1, 1);

  int bc = 0;
  for (int t = 0; t < T; ++t) {
    if (t < T - 1) {
      if constexpr (BN == 128)
        asm volatile("s_waitcnt vmcnt(4) lgkmcnt(0)" ::: "memory");
      else
        asm volatile("s_waitcnt vmcnt(3) lgkmcnt(0)" ::: "memory");
    } else {
      asm volatile("s_waitcnt vmcnt(0) lgkmcnt(0)" ::: "memory");
    }
    __builtin_amdgcn_s_barrier();
    if (t + 2 < T) { int bs = bc == 0 ? 2 : bc - 1; stage(t + 2, bs); }

    short8 af[4], bfr[NI];
#pragma unroll
    for (int mi = 0; mi < 4; mi++) af[mi] = ld8(&As[bc][(wr + mi * 16 + l15) * 32 + qq * 8]);
#pragma unroll
    for (int ni = 0; ni < NI; ni++) bfr[ni] = ld8(&Bs[bc][(wc + ni * 16 + l15) * 32 + qq * 8]);
#pragma unroll
    for (int mi = 0; mi < 4; mi++)
#pragma unroll
      for (int ni = 0; ni < NI; ni++)
        acc[mi][ni] = mfma16(af[mi], bfr[ni], acc[mi][ni]);
    bc = bc == 2 ? 0 : bc + 1;
  }

#pragma unroll
  for (int mi = 0; mi < 4; mi++) {
    int row = m0 + wr + mi * 16 + qq * 4;
#pragma unroll
    for (int ni = 0; ni < NI; ni++) {
      int col = n0 + wc + ni * 16 + l15;
      float bv = (MODE >= 1) ? bias[col] : 0.f;
#pragma unroll
      for (int r = 0; r < 4; r++) {
        float v = acc[mi][ni][r] + bv;
        size_t off = (size_t)(row + r) * Nn + col;
        if (MODE == 0) {
          outB[off] = __float2bfloat16(v);
        } else if (MODE == 2) {
          outB[off] = __float2bfloat16(0.5f * v * (1.f + erff(v * 0.70710678118654752f)));
        } else if (MODE == 1) {
          outF[off] = v;
        } else {
          outF[off] = v + resid[off];
        }
      }
    }
  }
}

// ---------------- flash attention v23: window-pipelined + XCD-grouped blocks -------
// 512 blocks (1-D grid), 256 thr; LDS 64KB; 2 blocks/CU, one dispatch round.
// XCD grouping: dispatched id L -> XCD = L%8 (heuristic). Decode so all 32
// q-blocks of one (h,split) combo land on ONE XCD: L = c%8 + 8*(q + 32*(c/8)),
// c = h*2+split. Each XCD then serves 2 combos: K/V 2MB + Q 2MB ~= its 4MB L2,
// so global_load_lds staging hits L2 (~200cy) instead of L3/HBM (~400-900cy) --
// directly shortens the exposed drain in this latency-bound kernel.
// Schedule per iter (R9): loads(w0)->QK(w0)->loads(w1)->QK(w1)->SM(w0)->PV(w0)->
// SM(w1)->PV(w1); l via MFMA ones-column; K staged permuted for K=32 PV.
__global__ __launch_bounds__(256, 2)
void attn_kernel(const bf16* __restrict__ QKV, const bf16* __restrict__ Vt,
                 const u64* __restrict__ adjbits, const float* __restrict__ adj_bias,
                 bf16* __restrict__ AOpart, float* __restrict__ lpart) {
  __shared__ alignas(16) bf16 Kf[2][16 * 512];  // frag fi=ni*4+kk: permuted K rows x 32 k-dims
  __shared__ alignas(16) bf16 Vf[2][16 * 512];  // frag fi=d*2+k2:  V^T[d*16+l15][kt+k2*32+..]
  const int L = blockIdx.x;
  const int xr = L & 7, rest = L >> 3;
  const int qi = rest & 31, chi = rest >> 5;
  const int c = xr + 8 * chi;
  const int h = c >> 1, split = c & 1;
  const int q0 = qi * 128;
  const int k0 = split * 2048;
  const int tid = threadIdx.x, wave = tid >> 6, lane = tid & 63;
  const int l15 = lane & 15, qq = lane >> 4;
  const float log2e = 1.4426950408889634f;
  const float beta2 = adj_bias[h] * log2e;
  const float scale2 = 0.08838834764831845f * log2e;  // 128^-0.5 * log2(e)

  // Q fragments (B-operand; 32 rows per wave)
  short8 qf[2][4];
#pragma unroll
  for (int mi = 0; mi < 2; mi++)
#pragma unroll
    for (int kk = 0; kk < 4; kk++)
      qf[mi][kk] = ld8(&QKV[(size_t)(q0 + wave * 32 + mi * 16 + l15) * 3072 +
                            h * 128 + kk * 32 + qq * 8]);

  floatx4 o[2][8];
#pragma unroll
  for (int mi = 0; mi < 2; mi++)
#pragma unroll
    for (int d = 0; d < 8; d++) o[mi][d] = (floatx4)0.f;
  floatx4 o8[2] = {(floatx4)0.f, (floatx4)0.f};   // l accumulator (D rows = q)
  short8 ones;
#pragma unroll
  for (int i = 0; i < 8; i++) ones[i] = (short)0x3F80;  // bf16 1.0

  const size_t abase = (size_t)(q0 + wave * 32 + l15) * 64 + split * 32;
  // key permutation within a 32-key window (slot l15 -> key offset), +4 for odd ni
  const int kperm = ((l15 >> 2) * 8) + (l15 & 3);

  auto stage = [&](int t, int buf) {
    const int kt = k0 + t * 64;
#pragma unroll
    for (int i = 0; i < 4; i++) {
      int fi = wave * 4 + i;
      int ni = fi >> 2, kk = fi & 3;
      int krow = kt + (ni >> 1) * 32 + (ni & 1) * 4 + kperm;
      load_lds16(&QKV[(size_t)krow * 3072 + 1024 + h * 128 + kk * 32 + qq * 8],
                 (char*)Kf[buf] + fi * 1024);
      int d = fi >> 1, k2 = fi & 1;
      load_lds16(&Vt[(size_t)(h * 128 + d * 16 + l15) * 4096 + kt + k2 * 32 + qq * 8],
                 (char*)Vf[buf] + fi * 1024);
    }
  };

  // prologue: stage tile 0, prefetch adj words for tile 0
  stage(0, 0);
  u64 a0c = adjbits[abase];
  u64 a1c = adjbits[abase + 1024];

  const int bp = qq * 8;

  for (int t = 0; t < 32; t++) {
    // __syncthreads drains this wave's in-flight stage+adj loads and makes
    // buf[t&1] visible; all waves are also done reading buf[(t+1)&1].
    __syncthreads();
    if (t < 31) stage(t + 1, (t + 1) & 1);
    u64 a0n = 0, a1n = 0;
    if (t < 31) { a0n = adjbits[abase + t + 1]; a1n = adjbits[abase + 1024 + t + 1]; }

    const bf16* Kc = Kf[t & 1];
    const char* Vcb = (const char*)Vf[t & 1];
    const uint32_t w0lo = (uint32_t)a0c, w0hi = (uint32_t)(a0c >> 32);
    const uint32_t w1lo = (uint32_t)a1c, w1hi = (uint32_t)(a1c >> 32);

    // ---- window 0 operand loads ----
    short8 k0r[8], v0r[8];
#pragma unroll
    for (int kk = 0; kk < 4; kk++) {
      k0r[kk]     = ld8(&Kc[(0 * 4 + kk) * 512 + lane * 8]);   // ni2=0, hh=0
      k0r[4 + kk] = ld8(&Kc[(1 * 4 + kk) * 512 + lane * 8]);   // ni2=0, hh=1
    }
#pragma unroll
    for (int d = 0; d < 8; d++)
      v0r[d] = ld8((const bf16*)(Vcb + (d * 2 + 0) * 1024 + qq * 256 + l15 * 16));

    // ---- QK window 0 (4 independent chains) ----
    floatx4 s00 = (floatx4)0.f, s10 = (floatx4)0.f;
    floatx4 s01 = (floatx4)0.f, s11 = (floatx4)0.f;
    __builtin_amdgcn_s_setprio(1);
#pragma unroll
    for (int kk = 0; kk < 4; kk++) {
      s00 = mfma16(k0r[kk], qf[0][kk], s00);
      s10 = mfma16(k0r[kk], qf[1][kk], s10);
    }
#pragma unroll
    for (int kk = 0; kk < 4; kk++) {
      s01 = mfma16(k0r[4 + kk], qf[0][kk], s01);
      s11 = mfma16(k0r[4 + kk], qf[1][kk], s11);
    }
    __builtin_amdgcn_s_setprio(0);

    // ---- window 1 operand loads (overlap SM0/PV0 VALU below) ----
    short8 k1r[8], v1r[8];
#pragma unroll
    for (int kk = 0; kk < 4; kk++) {
      k1r[kk]     = ld8(&Kc[(2 * 4 + kk) * 512 + lane * 8]);   // ni2=1, hh=0
      k1r[4 + kk] = ld8(&Kc[(3 * 4 + kk) * 512 + lane * 8]);   // ni2=1, hh=1
    }
#pragma unroll
    for (int d = 0; d < 8; d++)
      v1r[d] = ld8((const bf16*)(Vcb + (d * 2 + 1) * 1024 + qq * 256 + l15 * 16));

    // ---- QK window 1 ----
    floatx4 u00 = (floatx4)0.f, u10 = (floatx4)0.f;
    floatx4 u01 = (floatx4)0.f, u11 = (floatx4)0.f;
    __builtin_amdgcn_s_setprio(1);
#pragma unroll
    for (int kk = 0; kk < 4; kk++) {
      u00 = mfma16(k1r[kk], qf[0][kk], u00);
      u10 = mfma16(k1r[kk], qf[1][kk], u10);
    }
#pragma unroll
    for (int kk = 0; kk < 4; kk++) {
      u01 = mfma16(k1r[4 + kk], qf[0][kk], u01);
      u11 = mfma16(k1r[4 + kk], qf[1][kk], u11);
    }
    __builtin_amdgcn_s_setprio(0);

    // ---- SM window 0 ----
    short8 pa0, pa1;
    {
      short4v a = sm4(s00, w0lo, bp, scale2, beta2);
      short4v b = sm4(s01, w0lo >> 4, bp, scale2, beta2);
      pa0[0] = a.x; pa0[1] = a.y; pa0[2] = a.z; pa0[3] = a.w;
      pa0[4] = b.x; pa0[5] = b.y; pa0[6] = b.z; pa0[7] = b.w;
      a = sm4(s10, w1lo, bp, scale2, beta2);
      b = sm4(s11, w1lo >> 4, bp, scale2, beta2);
      pa1[0] = a.x; pa1[1] = a.y; pa1[2] = a.z; pa1[3] = a.w;
      pa1[4] = b.x; pa1[5] = b.y; pa1[6] = b.z; pa1[7] = b.w;
    }
    // ---- PV window 0 ----
    __builtin_amdgcn_s_setprio(1);
#pragma unroll
    for (int d = 0; d < 8; d++) {
      o[0][d] = mfma16(pa0, v0r[d], o[0][d]);
      o[1][d] = mfma16(pa1, v0r[d], o[1][d]);
    }
    o8[0] = mfma16(pa0, ones, o8[0]);
    o8[1] = mfma16(pa1, ones, o8[1]);
    __builtin_amdgcn_s_setprio(0);

    // ---- SM window 1 ----
    short8 pb0, pb1;
    {
      short4v a = sm4(u00, w0hi, bp, scale2, beta2);
      short4v b = sm4(u01, w0hi >> 4, bp, scale2, beta2);
      pb0[0] = a.x; pb0[1] = a.y; pb0[2] = a.z; pb0[3] = a.w;
      pb0[4] = b.x; pb0[5] = b.y; pb0[6] = b.z; pb0[7] = b.w;
      a = sm4(u10, w1hi, bp, scale2, beta2);
      b = sm4(u11, w1hi >> 4, bp, scale2, beta2);
      pb1[0] = a.x; pb1[1] = a.y; pb1[2] = a.z; pb1[3] = a.w;
      pb1[4] = b.x; pb1[5] = b.y; pb1[6] = b.z; pb1[7] = b.w;
    }
    // ---- PV window 1 ----
    __builtin_amdgcn_s_setprio(1);
#pragma unroll
    for (int d = 0; d < 8; d++) {
      o[0][d] = mfma16(pb0, v1r[d], o[0][d]);
      o[1][d] = mfma16(pb1, v1r[d], o[1][d]);
    }
    o8[0] = mfma16(pb0, ones, o8[0]);
    o8[1] = mfma16(pb1, ones, o8[1]);
    __builtin_amdgcn_s_setprio(0);

    a0c = a0n; a1c = a1n;
  }

  // epilogue: l comes straight out of o8 (D rows = q = qq*4+r); write bf16 partials
#pragma unroll
  for (int mi = 0; mi < 2; mi++) {
    if (l15 == 0) {
#pragma unroll
      for (int r = 0; r < 4; r++)
        lpart[((size_t)split * 4096 + q0 + wave * 32 + mi * 16 + qq * 4 + r) * 8 + h] =
            o8[mi][r];
    }
#pragma unroll
    for (int r = 0; r < 4; r++) {
      int grow = q0 + wave * 32 + mi * 16 + qq * 4 + r;
      bf16* dst = AOpart + ((size_t)split * 4096 + grow) * 1024 + h * 128;
#pragma unroll
      for (int d = 0; d < 8; d++) dst[d * 16 + l15] = __float2bfloat16(o[mi][d][r]);
    }
  }
}

// ---------------- combine split-K partials (2 splits), normalize -> bf16 AO ----------------
__global__ __launch_bounds__(256)
void attn_norm(const bf16* __restrict__ AOpart, const float* __restrict__ lpart,
               bf16* __restrict__ AO) {
  int row = blockIdx.x, tid = threadIdx.x;
  int h = tid >> 5;
  float ls = 0.f;
#pragma unroll
  for (int s = 0; s < 2; s++) ls += lpart[((size_t)s * 4096 + row) * 8 + h];
  float a0 = 0.f, a1 = 0.f, a2 = 0.f, a3 = 0.f;
#pragma unroll
  for (int s = 0; s < 2; s++) {
    short4v v = *(const short4v*)&AOpart[((size_t)s * 4096 + row) * 1024 + tid * 4];
    a0 += fbf(v.x); a1 += fbf(v.y); a2 += fbf(v.z); a3 += fbf(v.w);
  }
  float inv = 1.f / ls;
  bf16* op = AO + (size_t)row * 1024 + tid * 4;
  op[0] = __float2bfloat16(a0 * inv);
  op[1] = __float2bfloat16(a1 * inv);
  op[2] = __float2bfloat16(a2 * inv);
  op[3] = __float2bfloat16(a3 * inv);
}

// ---------------- fused double-LayerNorm ----------------
DEVI void block_sum2(float& a, float& b, float* red) {
#pragma unroll
  for (int o = 1; o < 64; o <<= 1) { a += __shfl_xor(a, o, 64); b += __shfl_xor(b, o, 64); }
  int wv = threadIdx.x >> 6;
  if ((threadIdx.x & 63) == 0) { red[wv] = a; red[4 + wv] = b; }
  __syncthreads();
  a = red[0] + red[1] + red[2] + red[3];
  b = red[4] + red[5] + red[6] + red[7];
  __syncthreads();
}

__global__ __launch_bounds__(256)
void ln2_kernel(const float* __restrict__ x, const float* __restrict__ ao,
                const float* __restrict__ g1, const float* __restrict__ b1,
                const float* __restrict__ g2, const float* __restrict__ b2,
                float* __restrict__ hout, bf16* __restrict__ fln) {
  __shared__ float red[8];
  const int row = blockIdx.x, tid = threadIdx.x;
  float4 xv = ((const float4*)(x + (size_t)row * 1024))[tid];
  float4 av = ((const float4*)(ao + (size_t)row * 1024))[tid];
  float s0 = xv.x + av.x, s1 = xv.y + av.y, s2 = xv.z + av.z, s3 = xv.w + av.w;
  float sum = s0 + s1 + s2 + s3;
  float ssq = s0 * s0 + s1 * s1 + s2 * s2 + s3 * s3;
  block_sum2(sum, ssq, red);
  float mu = sum * (1.f / 1024.f);
  float rs = rsqrtf(ssq * (1.f / 1024.f) - mu * mu + 1e-5f);
  float4 gv = ((const float4*)g1)[tid], bv = ((const float4*)b1)[tid];
  float h0 = (s0 - mu) * rs * gv.x + bv.x;
  float h1 = (s1 - mu) * rs * gv.y + bv.y;
  float h2 = (s2 - mu) * rs * gv.z + bv.z;
  float h3 = (s3 - mu) * rs * gv.w + bv.w;
  float4 hv; hv.x = h0; hv.y = h1; hv.z = h2; hv.w = h3;
  ((float4*)(hout + (size_t)row * 1024))[tid] = hv;
  float sum2 = h0 + h1 + h2 + h3;
  float ssq2 = h0 * h0 + h1 * h1 + h2 * h2 + h3 * h3;
  block_sum2(sum2, ssq2, red);
  float mu2 = sum2 * (1.f / 1024.f);
  float rs2 = rsqrtf(ssq2 * (1.f / 1024.f) - mu2 * mu2 + 1e-5f);
  float4 g2v = ((const float4*)g2)[tid], b2v = ((const float4*)b2)[tid];
  bf16* op = fln + (size_t)row * 1024 + tid * 4;
  op[0] = __float2bfloat16((h0 - mu2) * rs2 * g2v.x + b2v.x);
  op[1] = __float2bfloat16((h1 - mu2) * rs2 * g2v.y + b2v.y);
  op[2] = __float2bfloat16((h2 - mu2) * rs2 * g2v.z + b2v.z);
  op[3] = __float2bfloat16((h3 - mu2) * rs2 * g2v.w + b2v.w);
}

// ---------------- host launch ----------------
extern "C" void kernel_launch(void* const* d_in, const int* in_sizes, int n_in,
                              void* d_out, int out_size, void* d_ws, size_t ws_size,
                              hipStream_t stream) {
  const float* x    = (const float*)d_in[0];
  const float* adj  = (const float*)d_in[1];
  const float* Wq   = (const float*)d_in[2];
  const float* Wk   = (const float*)d_in[3];
  const float* Wv   = (const float*)d_in[4];
  const float* Wo   = (const float*)d_in[5];
  const float* Wob  = (const float*)d_in[6];
  const float* adjb = (const float*)d_in[7];
  const float* g1   = (const float*)d_in[8];
  const float* b1   = (const float*)d_in[9];
  const float* g2   = (const float*)d_in[10];
  const float* b2   = (const float*)d_in[11];
  const float* W1   = (const float*)d_in[12];
  const float* fb1  = (const float*)d_in[13];
  const float* W2   = (const float*)d_in[14];
  const float* fb2  = (const float*)d_in[15];
  float* out = (float*)d_out;

  char* w = (char*)d_ws;
  size_t off = 0;
  auto take = [&](size_t bytes) {
    char* p = w + off;
    off += (bytes + 255) & ~(size_t)255;
    return p;
  };
  bf16* xb    = (bf16*)take(4096ull * 1024 * 2);
  bf16* Wqkvt = (bf16*)take(3072ull * 1024 * 2);
  bf16* Wot   = (bf16*)take(1024ull * 1024 * 2);
  bf16* W1t   = (bf16*)take(2048ull * 1024 * 2);
  bf16* W2t   = (bf16*)take(1024ull * 2048 * 2);
  bf16* QKV   = (bf16*)take(4096ull * 3072 * 2);
  bf16* Vt    = (bf16*)take(1024ull * 4096 * 2);
  bf16* AO    = (bf16*)take(4096ull * 1024 * 2);
  u64*  adjbits = (u64*)take(4096ull * 64 * 8);
  float* lpart  = (float*)take(4ull * 4096 * 8 * 4);
  // 32MB region reused over time: AOpart (until attn_norm) -> WoP (after)
  char* big = take(32ull << 20);
  bf16*  AOpart = (bf16*)big;                       // 2 x 8MB bf16
  float* WoP    = (float*)big;                      // 16MB f32
  float* H   = (float*)take(4096ull * 1024 * 4);
  bf16*  FLN = (bf16*)take(4096ull * 1024 * 2);
  bf16*  G   = (bf16*)take(4096ull * 2048 * 2);

  dim3 tb(32, 8);
  // fused: x cvt + adj bits + all weight transposes (12288 blocks total)
  prep_all<<<12288, 256, 0, stream>>>(x, xb, adj, adjbits, Wq, Wk, Wv, Wo, W1, W2,
                                      Wqkvt, Wot, W1t, W2t);
  // QKV = xb @ [Wq|Wk|Wv]   (bf16 out)
  gemm_bt<0, 128><<<dim3(24, 32), 256, 0, stream>>>(xb, Wqkvt, nullptr, nullptr,
                                                    nullptr, QKV, 4096, 3072, 1024);
  // plain V^T per head: Vt[h*128+dh][n]
  tr_bf16t<<<dim3(32, 128), tb, 0, stream>>>(QKV + 2048, Vt, 3072);
  // flash attention, split-K x2, XCD-grouped 1-D grid (512 blocks)
  attn_kernel<<<512, 256, 0, stream>>>(QKV, Vt, adjbits, adjb, AOpart, lpart);
  attn_norm<<<4096, 256, 0, stream>>>(AOpart, lpart, AO);
  // WoP = AO @ Wo + Wo_b   (f32 out; 128x64 tiles -> 512 blocks, no split-K)
  gemm_bt<1, 64><<<dim3(16, 32), 256, 0, stream>>>(AO, Wot, Wob, nullptr,
                                                   WoP, nullptr, 4096, 1024, 1024);
  // h = LN(x + WoP); FLN = bf16(LN(h))
  ln2_kernel<<<4096, 256, 0, stream>>>(x, WoP, g1, b1, g2, b2, H, FLN);
  // G = gelu(FLN @ W1 + b1)   (bf16 out)
  gemm_bt<2, 128><<<dim3(16, 32), 256, 0, stream>>>(FLN, W1t, fb1, nullptr,
                                                    nullptr, G, 4096, 2048, 1024);
  // out = G @ W2 + b2 + h   (f32 out; 128x64 tiles -> 512 blocks, no split-K)
  gemm_bt<3, 64><<<dim3(16, 32), 256, 0, stream>>>(G, W2t, fb2, H,
                                                   out, nullptr, 4096, 1024, 2048);
}

// Round 11
// 402.951 us; speedup vs baseline: 1.3952x; 1.0053x over previous
//
#include <hip/hip_runtime.h>
#include <hip/hip_bf16.h>
#include <cstdint>
#include <cstddef>

typedef __hip_bfloat16 bf16;
typedef __attribute__((ext_vector_type(8))) short short8;
typedef __attribute__((ext_vector_type(4))) short short4v;
typedef __attribute__((ext_vector_type(4))) float floatx4;
typedef unsigned long long u64;

#define DEVI static __device__ __forceinline__

DEVI void load_lds16(const void* g, void* l) {
  __builtin_amdgcn_global_load_lds((const __attribute__((address_space(1))) unsigned int*)g,
                                   (__attribute__((address_space(3))) unsigned int*)l, 16, 0, 0);
}
DEVI short8 ld8(const bf16* p) { return *(const short8*)p; }
DEVI floatx4 mfma16(short8 a, short8 b, floatx4 c) {
  return __builtin_amdgcn_mfma_f32_16x16x32_bf16(a, b, c, 0, 0, 0);
}
DEVI short bfb(float f) { bf16 h = __float2bfloat16(f); return __builtin_bit_cast(short, h); }
DEVI float fbf(short s) { bf16 h = __builtin_bit_cast(bf16, s); return __bfloat162float(h); }

// softmax 4-pack: p = exp2(s*scale2 + bit?beta2:0) for 4 acc elems, bits u>>(bp+r)
DEVI short4v sm4(floatx4 s, uint32_t u, int bp, float scale2, float beta2) {
  short4v r;
  float p0 = __builtin_amdgcn_exp2f(fmaf(s[0], scale2, ((u >> (bp + 0)) & 1) ? beta2 : 0.f));
  float p1 = __builtin_amdgcn_exp2f(fmaf(s[1], scale2, ((u >> (bp + 1)) & 1) ? beta2 : 0.f));
  float p2 = __builtin_amdgcn_exp2f(fmaf(s[2], scale2, ((u >> (bp + 2)) & 1) ? beta2 : 0.f));
  float p3 = __builtin_amdgcn_exp2f(fmaf(s[3], scale2, ((u >> (bp + 3)) & 1) ? beta2 : 0.f));
  r.x = bfb(p0); r.y = bfb(p1); r.z = bfb(p2); r.w = bfb(p3);
  return r;
}

// ---------------- fused prep: x->bf16 + adj bits + all 6 weight transposes ----------------
// Block budget: 4096 (x/adj) + 4096 (Wq,Wk,Wv,Wo) + 2048 (W1) + 2048 (W2) = 12288.
DEVI void tr_tile(const float* in, bf16* out, int R, int C, int bx, int by) {
  __shared__ float t[32][33];
  int c0 = bx * 32, r0 = by * 32;
  int tx = threadIdx.x & 31, ty = threadIdx.x >> 5;
#pragma unroll
  for (int i = 0; i < 32; i += 8) t[ty + i][tx] = in[(size_t)(r0 + ty + i) * C + c0 + tx];
  __syncthreads();
#pragma unroll
  for (int i = 0; i < 32; i += 8)
    out[(size_t)(c0 + ty + i) * R + r0 + tx] = __float2bfloat16(t[tx][ty + i]);
}

__global__ __launch_bounds__(256)
void prep_all(const float* __restrict__ x, bf16* __restrict__ xb,
              const float* __restrict__ adj, u64* __restrict__ bits,
              const float* Wq, const float* Wk, const float* Wv, const float* Wo,
              const float* W1, const float* W2,
              bf16* Wqkvt, bf16* Wot, bf16* W1t, bf16* W2t) {
  int id = blockIdx.x;
  if (id < 4096) {
    const int row = id, tid = threadIdx.x;
    const int wave = tid >> 6, lane = tid & 63;
    float4 v = ((const float4*)(x + (size_t)row * 1024))[tid];
    bf16* o = xb + (size_t)row * 1024 + tid * 4;
    o[0] = __float2bfloat16(v.x); o[1] = __float2bfloat16(v.y);
    o[2] = __float2bfloat16(v.z); o[3] = __float2bfloat16(v.w);
    const float* arow = adj + (size_t)row * 4096;
#pragma unroll
    for (int it = 0; it < 16; it++) {
      int col = it * 256 + tid;
      u64 m = __ballot(arow[col] != 0.f);
      if (lane == 0) bits[(size_t)row * 64 + it * 4 + wave] = m;
    }
  } else if (id < 8192) {
    int q = id - 4096, w = q >> 10, t = q & 1023;
    const float* in = w == 0 ? Wq : w == 1 ? Wk : w == 2 ? Wv : Wo;
    bf16* out = w == 0 ? Wqkvt : w == 1 ? Wqkvt + 1024ull * 1024
              : w == 2 ? Wqkvt + 2048ull * 1024 : Wot;
    tr_tile(in, out, 1024, 1024, t & 31, t >> 5);
  } else if (id < 10240) {
    int t = id - 8192;
    tr_tile(W1, W1t, 1024, 2048, t & 63, t >> 6);
  } else {
    int t = id - 10240;
    tr_tile(W2, W2t, 2048, 1024, t & 31, t >> 5);
  }
}

// ---------------- plain V^T build: out[dh][n] = V[n][dh] ----------------
__global__ __launch_bounds__(256)
void tr_bf16t(const bf16* __restrict__ in, bf16* __restrict__ out, int inLd) {
  __shared__ bf16 t[32][33];
  int c0 = blockIdx.x * 32, r0 = blockIdx.y * 32;
  int tx = threadIdx.x, ty = threadIdx.y;
#pragma unroll
  for (int i = 0; i < 32; i += 8) t[ty + i][tx] = in[(size_t)(r0 + ty + i) * inLd + c0 + tx];
  __syncthreads();
#pragma unroll
  for (int i = 0; i < 32; i += 8)
    out[(size_t)(c0 + ty + i) * 4096 + r0 + tx] = t[tx][ty + i];
}

// ---------------- bf16 GEMM, C = A[M][K] @ Bt[N][K]^T, tile 128 x BN ----------------
// Pipelined K-loop: 3 LDS buffers, loads 2 tiles in flight, raw s_barrier with
// fine-grained vmcnt (never vmcnt(0) mid-loop). XCD-chunked block swizzle (T1).
// Occupancy: LDS = 3*(128+BN)*32*2B = 48KB (BN=128) / 36KB (BN=64) -> LDS permits
// 3 blocks/CU; __launch_bounds__(256,3) pins it (2nd arg = min BLOCKS/CU on this
// toolchain, R3/R6 lesson). Reg budget 512/3 = 170/wave total; body ~64 acc +
// ~100 VGPR = ~164 fits. 3 waves/SIMD vs 2 -> +50% latency hiding.
// MODE 0: bf16 C (QKV) | MODE 2: bf16 gelu(C+bias) (FFN1)
// MODE 1: f32 C + bias (Wo, BN=64) | MODE 3: f32 C + bias + resid (FFN2, BN=64)
template <int MODE, int BN>
__global__ __launch_bounds__(256, 3)
void gemm_bt(const bf16* __restrict__ A, const bf16* __restrict__ Bt,
             const float* __restrict__ bias, const float* __restrict__ resid,
             float* __restrict__ outF, bf16* __restrict__ outB,
             int M, int Nn, int K) {
  constexpr int NI = BN / 32;          // mfma col-tiles per wave
  __shared__ alignas(16) bf16 As[3][128 * 32];
  __shared__ alignas(16) bf16 Bs[3][BN * 32];
  const int tid = threadIdx.x;
  const int wave = tid >> 6, lane = tid & 63;
  // XCD-chunked swizzle: dispatched id L%8 = XCD (heuristic); XCD k gets a
  // CONTIGUOUS chunk of logical tiles -> neighbor tiles share A/B panels in L2.
  const int gx = gridDim.x, nwg = gx * gridDim.y;
  const int lin = blockIdx.x + gx * blockIdx.y;
  const int swz = (lin & 7) * (nwg >> 3) + (lin >> 3);
  const int m0 = (swz / gx) * 128, n0 = (swz % gx) * BN;
  const int wr = (wave >> 1) * 64, wc = (wave & 1) * (BN / 2);
  const int l15 = lane & 15, qq = lane >> 4;
  const int lr = lane >> 2, l4 = lane & 3;
  const int T = K >> 5;

  floatx4 acc[4][NI];
#pragma unroll
  for (int i = 0; i < 4; i++)
#pragma unroll
    for (int j = 0; j < NI; j++) acc[i][j] = (floatx4)0.f;

  const bf16* gA0 = A + (size_t)(m0 + wave * 16 + lr) * K + l4 * 8;
  const bf16* gA1 = gA0 + (size_t)64 * K;
  const bf16* gB0 = Bt + (size_t)(n0 + wave * 16 + lr) * K + l4 * 8;
  const bf16* gB1 = gB0 + (size_t)64 * K;
  const int lo = wave * 16 * 32;

  auto stage = [&](int t, int buf) {
    int kt = t * 32;
    load_lds16(gA0 + kt, &As[buf][lo]);
    load_lds16(gA1 + kt, &As[buf][64 * 32 + lo]);
    load_lds16(gB0 + kt, &Bs[buf][lo]);
    if (BN == 128) load_lds16(gB1 + kt, &Bs[buf][64 * 32 + lo]);
  };
  stage(0, 0);
  stage(1, 1);

  int bc = 0;
  for (int t = 0; t < T; ++t) {
    if (t < T - 1) {
      if constexpr (BN == 128)
        asm volatile("s_waitcnt vmcnt(4) lgkmcnt(0)" ::: "memory");
      else
        asm volatile("s_waitcnt vmcnt(3) lgkmcnt(0)" ::: "memory");
    } else {
      asm volatile("s_waitcnt vmcnt(0) lgkmcnt(0)" ::: "memory");
    }
    __builtin_amdgcn_s_barrier();
    if (t + 2 < T) { int bs = bc == 0 ? 2 : bc - 1; stage(t + 2, bs); }

    short8 af[4], bfr[NI];
#pragma unroll
    for (int mi = 0; mi < 4; mi++) af[mi] = ld8(&As[bc][(wr + mi * 16 + l15) * 32 + qq * 8]);
#pragma unroll
    for (int ni = 0; ni < NI; ni++) bfr[ni] = ld8(&Bs[bc][(wc + ni * 16 + l15) * 32 + qq * 8]);
#pragma unroll
    for (int mi = 0; mi < 4; mi++)
#pragma unroll
      for (int ni = 0; ni < NI; ni++)
        acc[mi][ni] = mfma16(af[mi], bfr[ni], acc[mi][ni]);
    bc = bc == 2 ? 0 : bc + 1;
  }

#pragma unroll
  for (int mi = 0; mi < 4; mi++) {
    int row = m0 + wr + mi * 16 + qq * 4;
#pragma unroll
    for (int ni = 0; ni < NI; ni++) {
      int col = n0 + wc + ni * 16 + l15;
      float bv = (MODE >= 1) ? bias[col] : 0.f;
#pragma unroll
      for (int r = 0; r < 4; r++) {
        float v = acc[mi][ni][r] + bv;
        size_t off = (size_t)(row + r) * Nn + col;
        if (MODE == 0) {
          outB[off] = __float2bfloat16(v);
        } else if (MODE == 2) {
          outB[off] = __float2bfloat16(0.5f * v * (1.f + erff(v * 0.70710678118654752f)));
        } else if (MODE == 1) {
          outF[off] = v;
        } else {
          outF[off] = v + resid[off];
        }
      }
    }
  }
}

// ---------------- flash attention v23: window-pipelined + XCD-grouped blocks -------
// 512 blocks (1-D grid), 256 thr; LDS 64KB; 2 blocks/CU, one dispatch round.
// XCD grouping (R10, CONFIRMED: FETCH 71.5->21.3MB): all 32 q-blocks of one
// (h,split) combo on one XCD -> K/V+Q fit its 4MB L2.
// Schedule per iter (R9): loads(w0)->QK(w0)->loads(w1)->QK(w1)->SM(w0)->PV(w0)->
// SM(w1)->PV(w1); l via MFMA ones-column; K staged permuted for K=32 PV.
__global__ __launch_bounds__(256, 2)
void attn_kernel(const bf16* __restrict__ QKV, const bf16* __restrict__ Vt,
                 const u64* __restrict__ adjbits, const float* __restrict__ adj_bias,
                 bf16* __restrict__ AOpart, float* __restrict__ lpart) {
  __shared__ alignas(16) bf16 Kf[2][16 * 512];  // frag fi=ni*4+kk: permuted K rows x 32 k-dims
  __shared__ alignas(16) bf16 Vf[2][16 * 512];  // frag fi=d*2+k2:  V^T[d*16+l15][kt+k2*32+..]
  const int L = blockIdx.x;
  const int xr = L & 7, rest = L >> 3;
  const int qi = rest & 31, chi = rest >> 5;
  const int c = xr + 8 * chi;
  const int h = c >> 1, split = c & 1;
  const int q0 = qi * 128;
  const int k0 = split * 2048;
  const int tid = threadIdx.x, wave = tid >> 6, lane = tid & 63;
  const int l15 = lane & 15, qq = lane >> 4;
  const float log2e = 1.4426950408889634f;
  const float beta2 = adj_bias[h] * log2e;
  const float scale2 = 0.08838834764831845f * log2e;  // 128^-0.5 * log2(e)

  // Q fragments (B-operand; 32 rows per wave)
  short8 qf[2][4];
#pragma unroll
  for (int mi = 0; mi < 2; mi++)
#pragma unroll
    for (int kk = 0; kk < 4; kk++)
      qf[mi][kk] = ld8(&QKV[(size_t)(q0 + wave * 32 + mi * 16 + l15) * 3072 +
                            h * 128 + kk * 32 + qq * 8]);

  floatx4 o[2][8];
#pragma unroll
  for (int mi = 0; mi < 2; mi++)
#pragma unroll
    for (int d = 0; d < 8; d++) o[mi][d] = (floatx4)0.f;
  floatx4 o8[2] = {(floatx4)0.f, (floatx4)0.f};   // l accumulator (D rows = q)
  short8 ones;
#pragma unroll
  for (int i = 0; i < 8; i++) ones[i] = (short)0x3F80;  // bf16 1.0

  const size_t abase = (size_t)(q0 + wave * 32 + l15) * 64 + split * 32;
  // key permutation within a 32-key window (slot l15 -> key offset), +4 for odd ni
  const int kperm = ((l15 >> 2) * 8) + (l15 & 3);

  auto stage = [&](int t, int buf) {
    const int kt = k0 + t * 64;
#pragma unroll
    for (int i = 0; i < 4; i++) {
      int fi = wave * 4 + i;
      int ni = fi >> 2, kk = fi & 3;
      int krow = kt + (ni >> 1) * 32 + (ni & 1) * 4 + kperm;
      load_lds16(&QKV[(size_t)krow * 3072 + 1024 + h * 128 + kk * 32 + qq * 8],
                 (char*)Kf[buf] + fi * 1024);
      int d = fi >> 1, k2 = fi & 1;
      load_lds16(&Vt[(size_t)(h * 128 + d * 16 + l15) * 4096 + kt + k2 * 32 + qq * 8],
                 (char*)Vf[buf] + fi * 1024);
    }
  };

  // prologue: stage tile 0, prefetch adj words for tile 0
  stage(0, 0);
  u64 a0c = adjbits[abase];
  u64 a1c = adjbits[abase + 1024];

  const int bp = qq * 8;

  for (int t = 0; t < 32; t++) {
    // __syncthreads drains this wave's in-flight stage+adj loads and makes
    // buf[t&1] visible; all waves are also done reading buf[(t+1)&1].
    __syncthreads();
    if (t < 31) stage(t + 1, (t + 1) & 1);
    u64 a0n = 0, a1n = 0;
    if (t < 31) { a0n = adjbits[abase + t + 1]; a1n = adjbits[abase + 1024 + t + 1]; }

    const bf16* Kc = Kf[t & 1];
    const char* Vcb = (const char*)Vf[t & 1];
    const uint32_t w0lo = (uint32_t)a0c, w0hi = (uint32_t)(a0c >> 32);
    const uint32_t w1lo = (uint32_t)a1c, w1hi = (uint32_t)(a1c >> 32);

    // ---- window 0 operand loads ----
    short8 k0r[8], v0r[8];
#pragma unroll
    for (int kk = 0; kk < 4; kk++) {
      k0r[kk]     = ld8(&Kc[(0 * 4 + kk) * 512 + lane * 8]);   // ni2=0, hh=0
      k0r[4 + kk] = ld8(&Kc[(1 * 4 + kk) * 512 + lane * 8]);   // ni2=0, hh=1
    }
#pragma unroll
    for (int d = 0; d < 8; d++)
      v0r[d] = ld8((const bf16*)(Vcb + (d * 2 + 0) * 1024 + qq * 256 + l15 * 16));

    // ---- QK window 0 (4 independent chains) ----
    floatx4 s00 = (floatx4)0.f, s10 = (floatx4)0.f;
    floatx4 s01 = (floatx4)0.f, s11 = (floatx4)0.f;
    __builtin_amdgcn_s_setprio(1);
#pragma unroll
    for (int kk = 0; kk < 4; kk++) {
      s00 = mfma16(k0r[kk], qf[0][kk], s00);
      s10 = mfma16(k0r[kk], qf[1][kk], s10);
    }
#pragma unroll
    for (int kk = 0; kk < 4; kk++) {
      s01 = mfma16(k0r[4 + kk], qf[0][kk], s01);
      s11 = mfma16(k0r[4 + kk], qf[1][kk], s11);
    }
    __builtin_amdgcn_s_setprio(0);

    // ---- window 1 operand loads (overlap SM0/PV0 VALU below) ----
    short8 k1r[8], v1r[8];
#pragma unroll
    for (int kk = 0; kk < 4; kk++) {
      k1r[kk]     = ld8(&Kc[(2 * 4 + kk) * 512 + lane * 8]);   // ni2=1, hh=0
      k1r[4 + kk] = ld8(&Kc[(3 * 4 + kk) * 512 + lane * 8]);   // ni2=1, hh=1
    }
#pragma unroll
    for (int d = 0; d < 8; d++)
      v1r[d] = ld8((const bf16*)(Vcb + (d * 2 + 1) * 1024 + qq * 256 + l15 * 16));

    // ---- QK window 1 ----
    floatx4 u00 = (floatx4)0.f, u10 = (floatx4)0.f;
    floatx4 u01 = (floatx4)0.f, u11 = (floatx4)0.f;
    __builtin_amdgcn_s_setprio(1);
#pragma unroll
    for (int kk = 0; kk < 4; kk++) {
      u00 = mfma16(k1r[kk], qf[0][kk], u00);
      u10 = mfma16(k1r[kk], qf[1][kk], u10);
    }
#pragma unroll
    for (int kk = 0; kk < 4; kk++) {
      u01 = mfma16(k1r[4 + kk], qf[0][kk], u01);
      u11 = mfma16(k1r[4 + kk], qf[1][kk], u11);
    }
    __builtin_amdgcn_s_setprio(0);

    // ---- SM window 0 ----
    short8 pa0, pa1;
    {
      short4v a = sm4(s00, w0lo, bp, scale2, beta2);
      short4v b = sm4(s01, w0lo >> 4, bp, scale2, beta2);
      pa0[0] = a.x; pa0[1] = a.y; pa0[2] = a.z; pa0[3] = a.w;
      pa0[4] = b.x; pa0[5] = b.y; pa0[6] = b.z; pa0[7] = b.w;
      a = sm4(s10, w1lo, bp, scale2, beta2);
      b = sm4(s11, w1lo >> 4, bp, scale2, beta2);
      pa1[0] = a.x; pa1[1] = a.y; pa1[2] = a.z; pa1[3] = a.w;
      pa1[4] = b.x; pa1[5] = b.y; pa1[6] = b.z; pa1[7] = b.w;
    }
    // ---- PV window 0 ----
    __builtin_amdgcn_s_setprio(1);
#pragma unroll
    for (int d = 0; d < 8; d++) {
      o[0][d] = mfma16(pa0, v0r[d], o[0][d]);
      o[1][d] = mfma16(pa1, v0r[d], o[1][d]);
    }
    o8[0] = mfma16(pa0, ones, o8[0]);
    o8[1] = mfma16(pa1, ones, o8[1]);
    __builtin_amdgcn_s_setprio(0);

    // ---- SM window 1 ----
    short8 pb0, pb1;
    {
      short4v a = sm4(u00, w0hi, bp, scale2, beta2);
      short4v b = sm4(u01, w0hi >> 4, bp, scale2, beta2);
      pb0[0] = a.x; pb0[1] = a.y; pb0[2] = a.z; pb0[3] = a.w;
      pb0[4] = b.x; pb0[5] = b.y; pb0[6] = b.z; pb0[7] = b.w;
      a = sm4(u10, w1hi, bp, scale2, beta2);
      b = sm4(u11, w1hi >> 4, bp, scale2, beta2);
      pb1[0] = a.x; pb1[1] = a.y; pb1[2] = a.z; pb1[3] = a.w;
      pb1[4] = b.x; pb1[5] = b.y; pb1[6] = b.z; pb1[7] = b.w;
    }
    // ---- PV window 1 ----
    __builtin_amdgcn_s_setprio(1);
#pragma unroll
    for (int d = 0; d < 8; d++) {
      o[0][d] = mfma16(pb0, v1r[d], o[0][d]);
      o[1][d] = mfma16(pb1, v1r[d], o[1][d]);
    }
    o8[0] = mfma16(pb0, ones, o8[0]);
    o8[1] = mfma16(pb1, ones, o8[1]);
    __builtin_amdgcn_s_setprio(0);

    a0c = a0n; a1c = a1n;
  }

  // epilogue: l comes straight out of o8 (D rows = q = qq*4+r); write bf16 partials
#pragma unroll
  for (int mi = 0; mi < 2; mi++) {
    if (l15 == 0) {
#pragma unroll
      for (int r = 0; r < 4; r++)
        lpart[((size_t)split * 4096 + q0 + wave * 32 + mi * 16 + qq * 4 + r) * 8 + h] =
            o8[mi][r];
    }
#pragma unroll
    for (int r = 0; r < 4; r++) {
      int grow = q0 + wave * 32 + mi * 16 + qq * 4 + r;
      bf16* dst = AOpart + ((size_t)split * 4096 + grow) * 1024 + h * 128;
#pragma unroll
      for (int d = 0; d < 8; d++) dst[d * 16 + l15] = __float2bfloat16(o[mi][d][r]);
    }
  }
}

// ---------------- combine split-K partials (2 splits), normalize -> bf16 AO ----------------
__global__ __launch_bounds__(256)
void attn_norm(const bf16* __restrict__ AOpart, const float* __restrict__ lpart,
               bf16* __restrict__ AO) {
  int row = blockIdx.x, tid = threadIdx.x;
  int h = tid >> 5;
  float ls = 0.f;
#pragma unroll
  for (int s = 0; s < 2; s++) ls += lpart[((size_t)s * 4096 + row) * 8 + h];
  float a0 = 0.f, a1 = 0.f, a2 = 0.f, a3 = 0.f;
#pragma unroll
  for (int s = 0; s < 2; s++) {
    short4v v = *(const short4v*)&AOpart[((size_t)s * 4096 + row) * 1024 + tid * 4];
    a0 += fbf(v.x); a1 += fbf(v.y); a2 += fbf(v.z); a3 += fbf(v.w);
  }
  float inv = 1.f / ls;
  bf16* op = AO + (size_t)row * 1024 + tid * 4;
  op[0] = __float2bfloat16(a0 * inv);
  op[1] = __float2bfloat16(a1 * inv);
  op[2] = __float2bfloat16(a2 * inv);
  op[3] = __float2bfloat16(a3 * inv);
}

// ---------------- fused double-LayerNorm ----------------
DEVI void block_sum2(float& a, float& b, float* red) {
#pragma unroll
  for (int o = 1; o < 64; o <<= 1) { a += __shfl_xor(a, o, 64); b += __shfl_xor(b, o, 64); }
  int wv = threadIdx.x >> 6;
  if ((threadIdx.x & 63) == 0) { red[wv] = a; red[4 + wv] = b; }
  __syncthreads();
  a = red[0] + red[1] + red[2] + red[3];
  b = red[4] + red[5] + red[6] + red[7];
  __syncthreads();
}

__global__ __launch_bounds__(256)
void ln2_kernel(const float* __restrict__ x, const float* __restrict__ ao,
                const float* __restrict__ g1, const float* __restrict__ b1,
                const float* __restrict__ g2, const float* __restrict__ b2,
                float* __restrict__ hout, bf16* __restrict__ fln) {
  __shared__ float red[8];
  const int row = blockIdx.x, tid = threadIdx.x;
  float4 xv = ((const float4*)(x + (size_t)row * 1024))[tid];
  float4 av = ((const float4*)(ao + (size_t)row * 1024))[tid];
  float s0 = xv.x + av.x, s1 = xv.y + av.y, s2 = xv.z + av.z, s3 = xv.w + av.w;
  float sum = s0 + s1 + s2 + s3;
  float ssq = s0 * s0 + s1 * s1 + s2 * s2 + s3 * s3;
  block_sum2(sum, ssq, red);
  float mu = sum * (1.f / 1024.f);
  float rs = rsqrtf(ssq * (1.f / 1024.f) - mu * mu + 1e-5f);
  float4 gv = ((const float4*)g1)[tid], bv = ((const float4*)b1)[tid];
  float h0 = (s0 - mu) * rs * gv.x + bv.x;
  float h1 = (s1 - mu) * rs * gv.y + bv.y;
  float h2 = (s2 - mu) * rs * gv.z + bv.z;
  float h3 = (s3 - mu) * rs * gv.w + bv.w;
  float4 hv; hv.x = h0; hv.y = h1; hv.z = h2; hv.w = h3;
  ((float4*)(hout + (size_t)row * 1024))[tid] = hv;
  float sum2 = h0 + h1 + h2 + h3;
  float ssq2 = h0 * h0 + h1 * h1 + h2 * h2 + h3 * h3;
  block_sum2(sum2, ssq2, red);
  float mu2 = sum2 * (1.f / 1024.f);
  float rs2 = rsqrtf(ssq2 * (1.f / 1024.f) - mu2 * mu2 + 1e-5f);
  float4 g2v = ((const float4*)g2)[tid], b2v = ((const float4*)b2)[tid];
  bf16* op = fln + (size_t)row * 1024 + tid * 4;
  op[0] = __float2bfloat16((h0 - mu2) * rs2 * g2v.x + b2v.x);
  op[1] = __float2bfloat16((h1 - mu2) * rs2 * g2v.y + b2v.y);
  op[2] = __float2bfloat16((h2 - mu2) * rs2 * g2v.z + b2v.z);
  op[3] = __float2bfloat16((h3 - mu2) * rs2 * g2v.w + b2v.w);
}

// ---------------- host launch ----------------
extern "C" void kernel_launch(void* const* d_in, const int* in_sizes, int n_in,
                              void* d_out, int out_size, void* d_ws, size_t ws_size,
                              hipStream_t stream) {
  const float* x    = (const float*)d_in[0];
  const float* adj  = (const float*)d_in[1];
  const float* Wq   = (const float*)d_in[2];
  const float* Wk   = (const float*)d_in[3];
  const float* Wv   = (const float*)d_in[4];
  const float* Wo   = (const float*)d_in[5];
  const float* Wob  = (const float*)d_in[6];
  const float* adjb = (const float*)d_in[7];
  const float* g1   = (const float*)d_in[8];
  const float* b1   = (const float*)d_in[9];
  const float* g2   = (const float*)d_in[10];
  const float* b2   = (const float*)d_in[11];
  const float* W1   = (const float*)d_in[12];
  const float* fb1  = (const float*)d_in[13];
  const float* W2   = (const float*)d_in[14];
  const float* fb2  = (const float*)d_in[15];
  float* out = (float*)d_out;

  char* w = (char*)d_ws;
  size_t off = 0;
  auto take = [&](size_t bytes) {
    char* p = w + off;
    off += (bytes + 255) & ~(size_t)255;
    return p;
  };
  bf16* xb    = (bf16*)take(4096ull * 1024 * 2);
  bf16* Wqkvt = (bf16*)take(3072ull * 1024 * 2);
  bf16* Wot   = (bf16*)take(1024ull * 1024 * 2);
  bf16* W1t   = (bf16*)take(2048ull * 1024 * 2);
  bf16* W2t   = (bf16*)take(1024ull * 2048 * 2);
  bf16* QKV   = (bf16*)take(4096ull * 3072 * 2);
  bf16* Vt    = (bf16*)take(1024ull * 4096 * 2);
  bf16* AO    = (bf16*)take(4096ull * 1024 * 2);
  u64*  adjbits = (u64*)take(4096ull * 64 * 8);
  float* lpart  = (float*)take(4ull * 4096 * 8 * 4);
  // 32MB region reused over time: AOpart (until attn_norm) -> WoP (after)
  char* big = take(32ull << 20);
  bf16*  AOpart = (bf16*)big;                       // 2 x 8MB bf16
  float* WoP    = (float*)big;                      // 16MB f32
  float* H   = (float*)take(4096ull * 1024 * 4);
  bf16*  FLN = (bf16*)take(4096ull * 1024 * 2);
  bf16*  G   = (bf16*)take(4096ull * 2048 * 2);

  dim3 tb(32, 8);
  // fused: x cvt + adj bits + all weight transposes (12288 blocks total)
  prep_all<<<12288, 256, 0, stream>>>(x, xb, adj, adjbits, Wq, Wk, Wv, Wo, W1, W2,
                                      Wqkvt, Wot, W1t, W2t);
  // QKV = xb @ [Wq|Wk|Wv]   (bf16 out)
  gemm_bt<0, 128><<<dim3(24, 32), 256, 0, stream>>>(xb, Wqkvt, nullptr, nullptr,
                                                    nullptr, QKV, 4096, 3072, 1024);
  // plain V^T per head: Vt[h*128+dh][n]
  tr_bf16t<<<dim3(32, 128), tb, 0, stream>>>(QKV + 2048, Vt, 3072);
  // flash attention, split-K x2, XCD-grouped 1-D grid (512 blocks)
  attn_kernel<<<512, 256, 0, stream>>>(QKV, Vt, adjbits, adjb, AOpart, lpart);
  attn_norm<<<4096, 256, 0, stream>>>(AOpart, lpart, AO);
  // WoP = AO @ Wo + Wo_b   (f32 out; 128x64 tiles -> 512 blocks, no split-K)
  gemm_bt<1, 64><<<dim3(16, 32), 256, 0, stream>>>(AO, Wot, Wob, nullptr,
                                                   WoP, nullptr, 4096, 1024, 1024);
  // h = LN(x + WoP); FLN = bf16(LN(h))
  ln2_kernel<<<4096, 256, 0, stream>>>(x, WoP, g1, b1, g2, b2, H, FLN);
  // G = gelu(FLN @ W1 + b1)   (bf16 out)
  gemm_bt<2, 128><<<dim3(16, 32), 256, 0, stream>>>(FLN, W1t, fb1, nullptr,
                                                    nullptr, G, 4096, 2048, 1024);
  // out = G @ W2 + b2 + h   (f32 out; 128x64 tiles -> 512 blocks, no split-K)
  gemm_bt<3, 64><<<dim3(16, 32), 256, 0, stream>>>(G, W2t, fb2, H,
                                                   out, nullptr, 4096, 1024, 2048);
}